// Round 2
// baseline (1354.907 us; speedup 1.0000x reference)
//
#include <hip/hip_runtime.h>

// Problem constants (from setup_inputs)
#define N_ATOM 2000
#define MNBR   12
#define OFEA   92
#define AF     64
#define BFEA   41
#define K1     169   // 2A+B
#define O1     128   // 2A
#define OE     82    // 2B
#define KPQ    105   // A+B
#define K3     274   // 3A+2B
#define NM     24000 // N*M
#define NCONV  3
#define HID    128
#define NCRY   64
#define EPS_BN 1e-5f

__device__ __forceinline__ float sigmoidf_(float x){ return 1.f/(1.f+__expf(-x)); }
__device__ __forceinline__ float softplusf_(float x){
    return fmaxf(x,0.f) + __logf(1.f + __expf(-fabsf(x)));
}

// ---------------- generic fp32 GEMM: C[r,o] = sum_k T[r*ldt+k]*W[o*ldw+k] + bias[o]
// 64 rows x 128 cols per block, 256 threads, 4x8 per thread (cols strided by 16).
#define BM 64
#define BN 128
#define BK 32

template<int EPI>  // 0 = none, 1 = softplus epilogue
__global__ __launch_bounds__(256)
void gemm_tn(const float* __restrict__ T, int ldt, int R,
             const float* __restrict__ W, int ldw, int K, int O,
             const float* __restrict__ bias,
             float* __restrict__ C, int ldc)
{
    __shared__ float Ts[BM][BK+1];
    __shared__ float Ws[BN][BK+1];
    const int tid = threadIdx.x;
    const int row0 = blockIdx.x * BM;
    const int tx = tid % 16;   // col group: cols tx + j*16
    const int ty = tid / 16;   // row group: rows ty*4 + i
    float acc[4][8];
    #pragma unroll
    for (int i=0;i<4;i++)
        #pragma unroll
        for (int j=0;j<8;j++) acc[i][j]=0.f;

    for (int k0 = 0; k0 < K; k0 += BK) {
        #pragma unroll
        for (int i=0;i<(BM*BK)/256;i++){
            int e = tid + i*256;
            int r = e / BK, k = e % BK;
            int gr = row0 + r, gk = k0 + k;
            Ts[r][k] = (gr < R && gk < K) ? T[(size_t)gr*ldt + gk] : 0.f;
        }
        #pragma unroll
        for (int i=0;i<(BN*BK)/256;i++){
            int e = tid + i*256;
            int r = e / BK, k = e % BK;
            int gk = k0 + k;
            Ws[r][k] = (r < O && gk < K) ? W[(size_t)r*ldw + gk] : 0.f;
        }
        __syncthreads();
        #pragma unroll
        for (int k=0;k<BK;k++){
            float a_[4], b_[8];
            #pragma unroll
            for (int i=0;i<4;i++) a_[i] = Ts[ty*4+i][k];
            #pragma unroll
            for (int j=0;j<8;j++) b_[j] = Ws[tx + j*16][k];
            #pragma unroll
            for (int i=0;i<4;i++)
                #pragma unroll
                for (int j=0;j<8;j++)
                    acc[i][j] += a_[i]*b_[j];
        }
        __syncthreads();
    }
    #pragma unroll
    for (int i=0;i<4;i++){
        int gr = row0 + ty*4 + i;
        if (gr >= R) continue;
        #pragma unroll
        for (int j=0;j<8;j++){
            int gc = tx + j*16;
            if (gc >= O) continue;
            float v = acc[i][j] + (bias ? bias[gc] : 0.f);
            if (EPI==1) v = softplusf_(v);
            C[(size_t)gr*ldc + gc] = v;
        }
    }
}

// ---------------- build tot[n,m,:] = [x[n], x[idx[n,m]], e[n,m]]
__global__ void gather_tot(float* __restrict__ TOT, const float* __restrict__ X,
                           const float* __restrict__ E, const int* __restrict__ idx,
                           int total)
{
    int i = blockIdx.x*blockDim.x + threadIdx.x;
    if (i >= total) return;
    int f = i % K1;
    int r = i / K1;      // n*12+m
    int n = r / MNBR;
    float v;
    if (f < AF)            v = X[n*AF + f];
    else if (f < 2*AF)     v = X[idx[r]*AF + (f-AF)];
    else                   v = E[r*BFEA + (f-2*AF)];
    TOT[i] = v;
}

// ---------------- per-column sum/sumsq (cols along fastest dim)
__global__ void bn_stats_cols(const float* __restrict__ C, int R, int O,
                              float* __restrict__ S1, float* __restrict__ S2)
{
    int t = threadIdx.x;
    if (t >= O) return;
    float s1 = 0.f, s2 = 0.f;
    for (int r = blockIdx.x; r < R; r += gridDim.x){
        float v = C[(size_t)r*O + t];
        s1 += v; s2 += v*v;
    }
    atomicAdd(&S1[t], s1);
    atomicAdd(&S2[t], s2);
}

__global__ void bn_finalize(const float* __restrict__ S1, const float* __restrict__ S2,
                            float invR, const float* __restrict__ g,
                            const float* __restrict__ b, int O,
                            float* __restrict__ s, float* __restrict__ t)
{
    int o = blockIdx.x*blockDim.x + threadIdx.x;
    if (o >= O) return;
    float mean = S1[o]*invR;
    float var  = fmaxf(S2[o]*invR - mean*mean, 0.f);
    float sc = g[o] / sqrtf(var + EPS_BN);
    s[o] = sc;
    t[o] = b[o] - sc*mean;
}

// ---------------- two-body: TB[n,a] = sum_m sig(bn(h[n,m,a])) * sp(bn(h[n,m,a+64]))
__global__ __launch_bounds__(64)
void two_body_k(const float* __restrict__ Hh, const float* __restrict__ sh,
                const float* __restrict__ th, float* __restrict__ TB)
{
    int n = blockIdx.x, a = threadIdx.x;
    float sa = sh[a], ta = th[a], sb = sh[AF+a], tb_ = th[AF+a];
    float acc = 0.f;
    #pragma unroll
    for (int m=0;m<MNBR;m++){
        const float* row = Hh + (size_t)(n*MNBR+m)*O1;
        acc += sigmoidf_(sa*row[a]+ta) * softplusf_(sb*row[AF+a]+tb_);
    }
    TB[n*AF+a] = acc;
}

// ---------------- edge update: e += sig(bn(he[:41])) * sp(bn(he[41:]))
__global__ void e_update_k(float* __restrict__ E, const float* __restrict__ HE,
                           const float* __restrict__ se, const float* __restrict__ te,
                           int total)
{
    int i = blockIdx.x*blockDim.x + threadIdx.x;
    if (i >= total) return;
    int b = i % BFEA, r = i / BFEA;
    float u = se[b]*HE[(size_t)r*OE + b] + te[b];
    float v = se[BFEA+b]*HE[(size_t)r*OE + BFEA + b] + te[BFEA+b];
    E[i] += sigmoidf_(u) * softplusf_(v);
}

// ---------------- repack W3 -> Wp (cols [Wj|Wij]), Wq (cols [Wl|Wil])
__global__ void repack_k(const float* __restrict__ W3i, float* __restrict__ WP,
                         float* __restrict__ WQ)
{
    int i = blockIdx.x*blockDim.x + threadIdx.x;
    if (i >= O1*KPQ) return;
    int o = i / KPQ, k = i % KPQ;
    int c1 = (k < AF) ? (AF + k)   : (3*AF + (k - AF));          // Wj | Wij
    int c2 = (k < AF) ? (2*AF + k) : (3*AF + BFEA + (k - AF));   // Wl | Wil
    WP[i] = W3i[o*K3 + c1];
    WQ[i] = W3i[o*K3 + c2];
}

// ---------------- closed-form BN3 stats: h3 = B + P_m + Q_l over (m,l)
__global__ __launch_bounds__(128)
void bn3_stats(const float* __restrict__ Bse, const float* __restrict__ P,
               const float* __restrict__ Q, int N,
               float* __restrict__ S1, float* __restrict__ S2)
{
    int o = threadIdx.x;            // 128
    int n0 = blockIdx.x * 16;
    float s1 = 0.f, s2 = 0.f;
    for (int a = 0; a < 16; a++){
        int n = n0 + a;
        if (n >= N) break;
        float B = Bse[(size_t)n*O1 + o];
        float sp=0.f, spp=0.f, sq=0.f, sqq=0.f;
        #pragma unroll
        for (int m=0;m<MNBR;m++){
            float p = P[(size_t)(n*MNBR+m)*O1 + o];
            sp += p; spp += p*p;
            float q = Q[(size_t)(n*MNBR+m)*O1 + o];
            sq += q; sqq += q*q;
        }
        s1 += 144.f*B + 12.f*(sp+sq);
        s2 += 144.f*B*B + 12.f*(spp+sqq) + 24.f*B*(sp+sq) + 2.f*sp*sq;
    }
    atomicAdd(&S1[o], s1);
    atomicAdd(&S2[o], s2);
}

// ---------------- three-body: TB[n,a] += sum_{m,l} sig(.)*sp(.), BN folded
__global__ __launch_bounds__(64)
void three_body_k(const float* __restrict__ Bse, const float* __restrict__ P,
                  const float* __restrict__ Q, const float* __restrict__ s3,
                  const float* __restrict__ t3, float* __restrict__ TB)
{
    int n = blockIdx.x, a = threadIdx.x;   // 64 threads
    float sa = s3[a], sb = s3[AF+a];
    float Ba = sa*Bse[(size_t)n*O1 + a]      + t3[a];
    float Bb = sb*Bse[(size_t)n*O1 + AF + a] + t3[AF+a];
    float Pa[MNBR], Pb[MNBR], Qa[MNBR], Qb[MNBR];
    #pragma unroll
    for (int m=0;m<MNBR;m++){
        size_t r = (size_t)(n*MNBR+m)*O1;
        Pa[m] = sa*P[r+a]; Pb[m] = sb*P[r+AF+a];
        Qa[m] = sa*Q[r+a]; Qb[m] = sb*Q[r+AF+a];
    }
    float acc = 0.f;
    #pragma unroll
    for (int m=0;m<MNBR;m++){
        float ua = Ba + Pa[m], ub = Bb + Pb[m];
        #pragma unroll
        for (int l=0;l<MNBR;l++){
            acc += sigmoidf_(ua + Qa[l]) * softplusf_(ub + Qb[l]);
        }
    }
    TB[n*AF+a] += acc;
}

// ---------------- x = softplus(x + bn2(TB))
__global__ void x_update_k(float* __restrict__ X, const float* __restrict__ TB,
                           const float* __restrict__ s2, const float* __restrict__ t2,
                           int total)
{
    int i = blockIdx.x*blockDim.x + threadIdx.x;
    if (i >= total) return;
    int a = i % AF;
    X[i] = softplusf_(X[i] + s2[a]*TB[i] + t2[a]);
}

__global__ void softplus_k(const float* __restrict__ in, float* __restrict__ out, int total)
{
    int i = blockIdx.x*blockDim.x + threadIdx.x;
    if (i >= total) return;
    out[i] = softplusf_(in[i]);
}

// ---------------- segment pooling
__global__ void pool_k(const float* __restrict__ Z, const int* __restrict__ seg,
                       float* __restrict__ POOL, float* __restrict__ CNT, int total)
{
    int i = blockIdx.x*blockDim.x + threadIdx.x;  // N*HID
    if (i >= total) return;
    int h = i % HID, n = i / HID;
    int s = seg[n];
    atomicAdd(&POOL[s*HID + h], Z[i]);
    if (h == 0) atomicAdd(&CNT[s], 1.f);
}

__global__ __launch_bounds__(64)
void out_k(const float* __restrict__ POOL, const float* __restrict__ CNT,
           const float* __restrict__ outW, const float* __restrict__ outb,
           float* __restrict__ out)
{
    int c = threadIdx.x;  // 64 crystals
    float cnt = fmaxf(CNT[c], 1.f);
    float s = 0.f;
    #pragma unroll 4
    for (int h=0;h<HID;h++) s += POOL[c*HID + h]*outW[h];
    out[c] = s/cnt + outb[0];
}

extern "C" void kernel_launch(void* const* d_in, const int* in_sizes, int n_in,
                              void* d_out, int out_size, void* d_ws, size_t ws_size,
                              hipStream_t stream)
{
    const float* atom_fea = (const float*)d_in[0];
    const float* nbr_fea  = (const float*)d_in[1];
    const int*   nbr_idx  = (const int*)d_in[2];
    const int*   site_seg = (const int*)d_in[3];
    const float* emb_W = (const float*)d_in[4];
    const float* emb_b = (const float*)d_in[5];
    const float* fcW   = (const float*)d_in[6];
    const float* fcb   = (const float*)d_in[7];
    const float* bn1_g = (const float*)d_in[8];
    const float* bn1_b = (const float*)d_in[9];
    const float* bn2_g = (const float*)d_in[10];
    const float* bn2_b = (const float*)d_in[11];
    const float* eW    = (const float*)d_in[12];
    const float* eb    = (const float*)d_in[13];
    const float* bne_g = (const float*)d_in[14];
    const float* bne_b = (const float*)d_in[15];
    const float* W3    = (const float*)d_in[16];
    const float* b3    = (const float*)d_in[17];
    const float* bn3_g = (const float*)d_in[18];
    const float* bn3_b = (const float*)d_in[19];
    const float* fc1W  = (const float*)d_in[20];
    const float* fc1b  = (const float*)d_in[21];
    const float* outW  = (const float*)d_in[22];
    const float* outb  = (const float*)d_in[23];

    // workspace layout (floats); total ~12.2M floats (~48.5 MB)
    float* ws   = (float*)d_ws;
    float* X    = ws;                    // 128000
    float* E    = ws + 128000;           // 984000
    float* TOT  = ws + 1112000;          // 4056000
    float* Hb   = ws + 5168000;          // 3072000 (h, then P)
    float* HEb  = ws + 8240000;          // 3072000 (he, then Q)
    float* BASE = ws + 11312000;         // 256000
    float* TB   = ws + 11568000;         // 128000
    float* ST   = ws + 11696000;         // 2048 stats
    float* WP   = ws + 11698048;         // 13440
    float* WQ   = WP + 13440;            // 13440
    float* XS   = ws + 11724928;         // 128000
    float* Z    = ws + 11852928;         // 256000
    float* POOL = ws + 12108928;         // 8192
    float* CNT  = POOL + 8192;           // 64

    float *S1h=ST+0,   *S2h=ST+128,  *sh=ST+256,  *th=ST+384;
    float *S1e=ST+512, *S2e=ST+640,  *se=ST+768,  *te=ST+896;
    float *S13=ST+1024,*S23=ST+1152, *s3=ST+1280, *t3=ST+1408;
    float *S12=ST+1536,*S22=ST+1600, *s2=ST+1664, *t2=ST+1728;

    // embedding: X = atom_fea @ emb_W^T + emb_b
    gemm_tn<0><<<(N_ATOM+BM-1)/BM, 256, 0, stream>>>(atom_fea, OFEA, N_ATOM,
                                                     emb_W, OFEA, OFEA, AF, emb_b, X, AF);
    // E = copy(nbr_fea)
    hipMemcpyAsync(E, nbr_fea, (size_t)NM*BFEA*sizeof(float),
                   hipMemcpyDeviceToDevice, stream);

    for (int i = 0; i < NCONV; i++){
        const float* fcW_i = fcW + (size_t)i*O1*K1;
        const float* fcb_i = fcb + i*O1;
        const float* g1 = bn1_g + i*O1, *b1 = bn1_b + i*O1;
        const float* g2 = bn2_g + i*AF, *b2 = bn2_b + i*AF;
        const float* eW_i = eW + (size_t)i*OE*K1;
        const float* eb_i = eb + i*OE;
        const float* ge = bne_g + i*OE, *be = bne_b + i*OE;
        const float* W3_i = W3 + (size_t)i*O1*K3;
        const float* b3_i = b3 + i*O1;
        const float* g3 = bn3_g + i*O1, *b3b = bn3_b + i*O1;

        hipMemsetAsync(ST, 0, 2048*sizeof(float), stream);

        gather_tot<<<(NM*K1+255)/256, 256, 0, stream>>>(TOT, X, E, nbr_idx, NM*K1);

        // h = tot @ fcW^T + fcb ; he = tot @ eW^T + eb
        gemm_tn<0><<<NM/BM, 256, 0, stream>>>(TOT, K1, NM, fcW_i, K1, K1, O1, fcb_i, Hb, O1);
        gemm_tn<0><<<NM/BM, 256, 0, stream>>>(TOT, K1, NM, eW_i,  K1, K1, OE, eb_i, HEb, OE);

        bn_stats_cols<<<128, 128, 0, stream>>>(Hb, NM, O1, S1h, S2h);
        bn_finalize<<<1, 128, 0, stream>>>(S1h, S2h, 1.f/NM, g1, b1, O1, sh, th);
        two_body_k<<<N_ATOM, 64, 0, stream>>>(Hb, sh, th, TB);

        bn_stats_cols<<<128, 128, 0, stream>>>(HEb, NM, OE, S1e, S2e);
        bn_finalize<<<1, 128, 0, stream>>>(S1e, S2e, 1.f/NM, ge, be, OE, se, te);
        e_update_k<<<(NM*BFEA+255)/256, 256, 0, stream>>>(E, HEb, se, te, NM*BFEA);

        // P,Q,base (Hb/HEb reused; h/he consumed above)
        // NOTE: [xn|e] slice of each tot row starts at offset AF (not 2*AF!)
        repack_k<<<(O1*KPQ+255)/256, 256, 0, stream>>>(W3_i, WP, WQ);
        gemm_tn<0><<<NM/BM, 256, 0, stream>>>(TOT+AF, K1, NM, WP, KPQ, KPQ, O1, nullptr, Hb, O1);
        gemm_tn<0><<<NM/BM, 256, 0, stream>>>(TOT+AF, K1, NM, WQ, KPQ, KPQ, O1, nullptr, HEb, O1);
        gemm_tn<0><<<(N_ATOM+BM-1)/BM, 256, 0, stream>>>(X, AF, N_ATOM, W3_i, K3, AF, O1, b3_i, BASE, O1);

        bn3_stats<<<(N_ATOM+15)/16, 128, 0, stream>>>(BASE, Hb, HEb, N_ATOM, S13, S23);
        bn_finalize<<<1, 128, 0, stream>>>(S13, S23, 1.f/(NM*MNBR), g3, b3b, O1, s3, t3);
        three_body_k<<<N_ATOM, 64, 0, stream>>>(BASE, Hb, HEb, s3, t3, TB);

        bn_stats_cols<<<128, 128, 0, stream>>>(TB, N_ATOM, AF, S12, S22);
        bn_finalize<<<1, 64, 0, stream>>>(S12, S22, 1.f/N_ATOM, g2, b2, AF, s2, t2);
        x_update_k<<<(N_ATOM*AF+255)/256, 256, 0, stream>>>(X, TB, s2, t2, N_ATOM*AF);
    }

    // head: z = softplus(softplus(x) @ fc1W^T + fc1b)
    softplus_k<<<(N_ATOM*AF+255)/256, 256, 0, stream>>>(X, XS, N_ATOM*AF);
    gemm_tn<1><<<(N_ATOM+BM-1)/BM, 256, 0, stream>>>(XS, AF, N_ATOM, fc1W, AF, AF, HID, fc1b, Z, HID);

    hipMemsetAsync(POOL, 0, (8192+64)*sizeof(float), stream);
    pool_k<<<(N_ATOM*HID+255)/256, 256, 0, stream>>>(Z, site_seg, POOL, CNT, N_ATOM*HID);
    out_k<<<1, 64, 0, stream>>>(POOL, CNT, outW, outb, (float*)d_out);
}

// Round 3
// 771.161 us; speedup vs baseline: 1.7570x; 1.7570x over previous
//
#include <hip/hip_runtime.h>

// Problem constants (from setup_inputs)
#define N_ATOM 2000
#define MNBR   12
#define OFEA   92
#define AF     64
#define BFEA   41
#define K1     169   // 2A+B
#define O1     128   // 2A
#define OE     82    // 2B
#define K3     274   // 3A+2B
#define NM     24000 // N*M
#define NCONV  3
#define HID    128
#define NCRY   64
#define EPS_BN 1e-5f

#define LDT    176   // padded TOT leading dim (16-float aligned)
#define LDH    256   // HB leading dim
#define KA_T   11    // ceil(176/16) k-tiles for GEMM_A
#define KB_T   7     // 112/16 k-tiles for GEMM_B
#define LWA    176   // packed WA leading dim
#define LWB    112   // packed WPQ leading dim

__device__ __forceinline__ float sigmoidf_(float x){ return 1.f/(1.f+__expf(-x)); }
__device__ __forceinline__ float softplusf_(float x){
    return fmaxf(x,0.f) + __logf(1.f + __expf(-fabsf(x)));
}

// ============ fast fp32 GEMM: C[r,c] = bias[c] + sum_k A[r*lda+k]*W[c*ldw+k]
// 128x128 tile, 256 threads, 8x8/thread in 4 quadrants (rows 4ty+i / 64+4ty+i,
// cols 4tx+j / 64+4tx+j) -> all LDS fragment reads are float4, <=2-way bank alias.
// K handled as KT full 16-wide tiles (A and W zero-padded in k, W zero-padded in
// cols to 256) -> no k/col guards. Double-buffered LDS, global->reg->LDS pipeline.
__global__ __launch_bounds__(256, 2)
void gemm_f(const float* __restrict__ A, int lda, int R,
            const float* __restrict__ W, int ldw, int KT,
            const float* __restrict__ bias,
            float* __restrict__ C, int ldc)
{
    __shared__ float As[2][16][132];
    __shared__ float Ws[2][16][132];
    const int tid  = threadIdx.x;
    const int row0 = blockIdx.x * 128;
    const int col0 = blockIdx.y * 128;
    const int tx = tid & 15, ty = tid >> 4;
    const int lr = tid >> 2;          // 0..63
    const int lk = (tid & 3) << 2;    // 0,4,8,12

    float acc[8][8];
    #pragma unroll
    for (int i=0;i<8;i++)
        #pragma unroll
        for (int j=0;j<8;j++) acc[i][j]=0.f;

    float4 ra0, ra1, rb0, rb1;
    const float4 z4 = make_float4(0.f,0.f,0.f,0.f);

    { // prologue: k-tile 0
        int r0 = row0 + lr, r1 = r0 + 64;
        ra0 = (r0 < R) ? *(const float4*)(A + (size_t)r0*lda + lk) : z4;
        ra1 = (r1 < R) ? *(const float4*)(A + (size_t)r1*lda + lk) : z4;
        rb0 = *(const float4*)(W + (size_t)(col0+lr)*ldw + lk);
        rb1 = *(const float4*)(W + (size_t)(col0+64+lr)*ldw + lk);
    }
    int buf = 0;
    for (int it = 0; it < KT; ++it){
        As[buf][lk+0][lr] = ra0.x; As[buf][lk+1][lr] = ra0.y;
        As[buf][lk+2][lr] = ra0.z; As[buf][lk+3][lr] = ra0.w;
        As[buf][lk+0][64+lr] = ra1.x; As[buf][lk+1][64+lr] = ra1.y;
        As[buf][lk+2][64+lr] = ra1.z; As[buf][lk+3][64+lr] = ra1.w;
        Ws[buf][lk+0][lr] = rb0.x; Ws[buf][lk+1][lr] = rb0.y;
        Ws[buf][lk+2][lr] = rb0.z; Ws[buf][lk+3][lr] = rb0.w;
        Ws[buf][lk+0][64+lr] = rb1.x; Ws[buf][lk+1][64+lr] = rb1.y;
        Ws[buf][lk+2][64+lr] = rb1.z; Ws[buf][lk+3][64+lr] = rb1.w;
        __syncthreads();
        if (it+1 < KT){
            int k = (it+1)*16 + lk;
            int r0 = row0 + lr, r1 = r0 + 64;
            ra0 = (r0 < R) ? *(const float4*)(A + (size_t)r0*lda + k) : z4;
            ra1 = (r1 < R) ? *(const float4*)(A + (size_t)r1*lda + k) : z4;
            rb0 = *(const float4*)(W + (size_t)(col0+lr)*ldw + k);
            rb1 = *(const float4*)(W + (size_t)(col0+64+lr)*ldw + k);
        }
        #pragma unroll
        for (int k=0;k<16;k++){
            float4 a0 = *(const float4*)&As[buf][k][4*ty];
            float4 a1 = *(const float4*)&As[buf][k][64+4*ty];
            float4 b0 = *(const float4*)&Ws[buf][k][4*tx];
            float4 b1 = *(const float4*)&Ws[buf][k][64+4*tx];
            float av[8] = {a0.x,a0.y,a0.z,a0.w,a1.x,a1.y,a1.z,a1.w};
            float bv[8] = {b0.x,b0.y,b0.z,b0.w,b1.x,b1.y,b1.z,b1.w};
            #pragma unroll
            for (int i=0;i<8;i++)
                #pragma unroll
                for (int j=0;j<8;j++)
                    acc[i][j] += av[i]*bv[j];
        }
        buf ^= 1;
    }
    float4 bias0 = z4, bias1 = z4;
    if (bias){
        bias0 = *(const float4*)(bias + col0 + 4*tx);
        bias1 = *(const float4*)(bias + col0 + 64 + 4*tx);
    }
    #pragma unroll
    for (int i=0;i<8;i++){
        int gr = row0 + ((i<4) ? (4*ty + i) : (64 + 4*ty + (i-4)));
        if (gr >= R) continue;
        float4 o0 = make_float4(acc[i][0]+bias0.x, acc[i][1]+bias0.y,
                                acc[i][2]+bias0.z, acc[i][3]+bias0.w);
        float4 o1 = make_float4(acc[i][4]+bias1.x, acc[i][5]+bias1.y,
                                acc[i][6]+bias1.z, acc[i][7]+bias1.w);
        *(float4*)(C + (size_t)gr*ldc + col0 + 4*tx) = o0;
        *(float4*)(C + (size_t)gr*ldc + col0 + 64 + 4*tx) = o1;
    }
}

// ============ small generic fp32 GEMM (embedding / BASE / head)
#define BM 64
#define BN 128
#define BK 32
template<int EPI>
__global__ __launch_bounds__(256)
void gemm_tn(const float* __restrict__ T, int ldt, int R,
             const float* __restrict__ W, int ldw, int K, int O,
             const float* __restrict__ bias,
             float* __restrict__ C, int ldc)
{
    __shared__ float Ts[BM][BK+1];
    __shared__ float Ws[BN][BK+1];
    const int tid = threadIdx.x;
    const int row0 = blockIdx.x * BM;
    const int tx = tid % 16;
    const int ty = tid / 16;
    float acc[4][8];
    #pragma unroll
    for (int i=0;i<4;i++)
        #pragma unroll
        for (int j=0;j<8;j++) acc[i][j]=0.f;

    for (int k0 = 0; k0 < K; k0 += BK) {
        #pragma unroll
        for (int i=0;i<(BM*BK)/256;i++){
            int e = tid + i*256;
            int r = e / BK, k = e % BK;
            int gr = row0 + r, gk = k0 + k;
            Ts[r][k] = (gr < R && gk < K) ? T[(size_t)gr*ldt + gk] : 0.f;
        }
        #pragma unroll
        for (int i=0;i<(BN*BK)/256;i++){
            int e = tid + i*256;
            int r = e / BK, k = e % BK;
            int gk = k0 + k;
            Ws[r][k] = (r < O && gk < K) ? W[(size_t)r*ldw + gk] : 0.f;
        }
        __syncthreads();
        #pragma unroll
        for (int k=0;k<BK;k++){
            float a_[4], b_[8];
            #pragma unroll
            for (int i=0;i<4;i++) a_[i] = Ts[ty*4+i][k];
            #pragma unroll
            for (int j=0;j<8;j++) b_[j] = Ws[tx + j*16][k];
            #pragma unroll
            for (int i=0;i<4;i++)
                #pragma unroll
                for (int j=0;j<8;j++)
                    acc[i][j] += a_[i]*b_[j];
        }
        __syncthreads();
    }
    #pragma unroll
    for (int i=0;i<4;i++){
        int gr = row0 + ty*4 + i;
        if (gr >= R) continue;
        #pragma unroll
        for (int j=0;j<8;j++){
            int gc = tx + j*16;
            if (gc >= O) continue;
            float v = acc[i][j] + (bias ? bias[gc] : 0.f);
            if (EPI==1) v = softplusf_(v);
            C[(size_t)gr*ldc + gc] = v;
        }
    }
}

// ============ pack all layer weights once: WA[3][256][176], WPQ[3][256][112], BIAS[3][256]
__global__ void pack_all(const float* __restrict__ fcW, const float* __restrict__ eW,
                         const float* __restrict__ W3, const float* __restrict__ fcb,
                         const float* __restrict__ eb,
                         float* __restrict__ WA, float* __restrict__ WPQ,
                         float* __restrict__ BIAS)
{
    int i = blockIdx.x*blockDim.x + threadIdx.x;
    const int nWA = NCONV*256*LWA;        // 135168
    const int nWB = NCONV*256*LWB;        // 86016
    if (i < nWA){
        int l = i/(256*LWA), rem = i%(256*LWA);
        int c = rem/LWA, k = rem%LWA;
        float v = 0.f;
        if (k < K1){
            if (c < O1)           v = fcW[((size_t)l*O1 + c)*K1 + k];
            else if (c < O1+OE)   v = eW[((size_t)l*OE + (c-O1))*K1 + k];
        }
        WA[i] = v;
    } else if (i < nWA + nWB){
        int j = i - nWA;
        int l = j/(256*LWB), rem = j%(256*LWB);
        int c = rem/LWB, k = rem%LWB;
        float v = 0.f;
        const float* W3l = W3 + (size_t)l*O1*K3;
        if (c < O1){          // P weights: [Wj | Wij]
            if (k < AF)            v = W3l[(size_t)c*K3 + AF + k];
            else if (k < AF+BFEA)  v = W3l[(size_t)c*K3 + 3*AF + (k-AF)];
        } else {              // Q weights: [Wl | Wil]
            int o = c - O1;
            if (k < AF)            v = W3l[(size_t)o*K3 + 2*AF + k];
            else if (k < AF+BFEA)  v = W3l[(size_t)o*K3 + 3*AF+BFEA + (k-AF)];
        }
        WPQ[j] = v;
    } else if (i < nWA + nWB + NCONV*256){
        int m = i - nWA - nWB;
        int l = m/256, c = m%256;
        float v = 0.f;
        if (c < O1)         v = fcb[l*O1 + c];
        else if (c < O1+OE) v = eb[l*OE + (c-O1)];
        BIAS[m] = v;
    }
}

// ============ tot[n,m,:] = [x[n] | x[idx[n,m]] | e[n,m] | 0-pad], lda=176
__global__ void gather_tot(float* __restrict__ TOT, const float* __restrict__ X,
                           const float* __restrict__ E, const int* __restrict__ idx,
                           int total)
{
    int i = blockIdx.x*blockDim.x + threadIdx.x;
    if (i >= total) return;
    int f = i % LDT;
    int r = i / LDT;
    int n = r / MNBR;
    float v = 0.f;
    if (f < AF)            v = X[n*AF + f];
    else if (f < 2*AF)     v = X[idx[r]*AF + (f-AF)];
    else if (f < K1)       v = E[r*BFEA + (f-2*AF)];
    TOT[i] = v;
}

// ============ per-column sum/sumsq over rows (ld-strided)
__global__ void bn_stats_cols(const float* __restrict__ C, int ld, int R, int O,
                              float* __restrict__ S1, float* __restrict__ S2)
{
    int t = threadIdx.x;
    if (t >= O) return;
    float s1 = 0.f, s2 = 0.f;
    for (int r = blockIdx.x; r < R; r += gridDim.x){
        float v = C[(size_t)r*ld + t];
        s1 += v; s2 += v*v;
    }
    atomicAdd(&S1[t], s1);
    atomicAdd(&S2[t], s2);
}

__global__ void bn_finalize(const float* __restrict__ S1, const float* __restrict__ S2,
                            float invR, const float* __restrict__ g,
                            const float* __restrict__ b, int O,
                            float* __restrict__ s, float* __restrict__ t)
{
    int o = blockIdx.x*blockDim.x + threadIdx.x;
    if (o >= O) return;
    float mean = S1[o]*invR;
    float var  = fmaxf(S2[o]*invR - mean*mean, 0.f);
    float sc = g[o] / sqrtf(var + EPS_BN);
    s[o] = sc;
    t[o] = b[o] - sc*mean;
}

// two-range finalize for packed [h(128) | he(82)] stats
__global__ void bn_finalize2(const float* __restrict__ S1, const float* __restrict__ S2,
                             float invR, const float* __restrict__ g1,
                             const float* __restrict__ b1,
                             const float* __restrict__ g2,
                             const float* __restrict__ b2,
                             float* __restrict__ s, float* __restrict__ t)
{
    int o = threadIdx.x;
    if (o >= O1+OE) return;
    float g = (o < O1) ? g1[o] : g2[o-O1];
    float b = (o < O1) ? b1[o] : b2[o-O1];
    float mean = S1[o]*invR;
    float var  = fmaxf(S2[o]*invR - mean*mean, 0.f);
    float sc = g / sqrtf(var + EPS_BN);
    s[o] = sc;
    t[o] = b - sc*mean;
}

// ============ two-body: TB[n,a] = sum_m sig(bn(h[.,a])) * sp(bn(h[.,64+a]))
__global__ __launch_bounds__(64)
void two_body_k(const float* __restrict__ HB, const float* __restrict__ sA,
                const float* __restrict__ tA, float* __restrict__ TB)
{
    int n = blockIdx.x, a = threadIdx.x;
    float sa = sA[a], ta = tA[a], sb = sA[AF+a], tb_ = tA[AF+a];
    float acc = 0.f;
    #pragma unroll
    for (int m=0;m<MNBR;m++){
        const float* row = HB + (size_t)(n*MNBR+m)*LDH;
        acc += sigmoidf_(sa*row[a]+ta) * softplusf_(sb*row[AF+a]+tb_);
    }
    TB[n*AF+a] = acc;
}

// ============ edge update: e += sig(bn(he[:41])) * sp(bn(he[41:])), he at cols 128..209
__global__ void e_update_k(float* __restrict__ E, const float* __restrict__ HB,
                           const float* __restrict__ sA, const float* __restrict__ tA,
                           int total)
{
    int i = blockIdx.x*blockDim.x + threadIdx.x;
    if (i >= total) return;
    int b = i % BFEA, r = i / BFEA;
    float u = sA[O1+b]*HB[(size_t)r*LDH + O1 + b] + tA[O1+b];
    float v = sA[O1+BFEA+b]*HB[(size_t)r*LDH + O1 + BFEA + b] + tA[O1+BFEA+b];
    E[i] += sigmoidf_(u) * softplusf_(v);
}

// ============ closed-form BN3 stats: h3 = B + P_m + Q_l ; P at cols 0..127, Q at 128..255
__global__ __launch_bounds__(128)
void bn3_stats(const float* __restrict__ Bse, const float* __restrict__ HB, int N,
               float* __restrict__ S1, float* __restrict__ S2)
{
    int o = threadIdx.x;
    int n0 = blockIdx.x * 16;
    float s1 = 0.f, s2 = 0.f;
    for (int a = 0; a < 16; a++){
        int n = n0 + a;
        if (n >= N) break;
        float B = Bse[(size_t)n*O1 + o];
        float sp=0.f, spp=0.f, sq=0.f, sqq=0.f;
        #pragma unroll
        for (int m=0;m<MNBR;m++){
            const float* row = HB + (size_t)(n*MNBR+m)*LDH;
            float p = row[o];
            sp += p; spp += p*p;
            float q = row[O1 + o];
            sq += q; sqq += q*q;
        }
        s1 += 144.f*B + 12.f*(sp+sq);
        s2 += 144.f*B*B + 12.f*(spp+sqq) + 24.f*B*(sp+sq) + 2.f*sp*sq;
    }
    atomicAdd(&S1[o], s1);
    atomicAdd(&S2[o], s2);
}

// ============ three-body accumulate into TB
__global__ __launch_bounds__(64)
void three_body_k(const float* __restrict__ Bse, const float* __restrict__ HB,
                  const float* __restrict__ s3, const float* __restrict__ t3,
                  float* __restrict__ TB)
{
    int n = blockIdx.x, a = threadIdx.x;
    float sa = s3[a], sb = s3[AF+a];
    float Ba = sa*Bse[(size_t)n*O1 + a]      + t3[a];
    float Bb = sb*Bse[(size_t)n*O1 + AF + a] + t3[AF+a];
    float Pa[MNBR], Pb[MNBR], Qa[MNBR], Qb[MNBR];
    #pragma unroll
    for (int m=0;m<MNBR;m++){
        const float* row = HB + (size_t)(n*MNBR+m)*LDH;
        Pa[m] = sa*row[a];      Pb[m] = sb*row[AF+a];
        Qa[m] = sa*row[O1+a];   Qb[m] = sb*row[O1+AF+a];
    }
    float acc = 0.f;
    #pragma unroll
    for (int m=0;m<MNBR;m++){
        float ua = Ba + Pa[m], ub = Bb + Pb[m];
        #pragma unroll
        for (int l=0;l<MNBR;l++){
            acc += sigmoidf_(ua + Qa[l]) * softplusf_(ub + Qb[l]);
        }
    }
    TB[n*AF+a] += acc;
}

__global__ void x_update_k(float* __restrict__ X, const float* __restrict__ TB,
                           const float* __restrict__ s2, const float* __restrict__ t2,
                           int total)
{
    int i = blockIdx.x*blockDim.x + threadIdx.x;
    if (i >= total) return;
    int a = i % AF;
    X[i] = softplusf_(X[i] + s2[a]*TB[i] + t2[a]);
}

__global__ void softplus_k(const float* __restrict__ in, float* __restrict__ out, int total)
{
    int i = blockIdx.x*blockDim.x + threadIdx.x;
    if (i >= total) return;
    out[i] = softplusf_(in[i]);
}

__global__ void pool_k(const float* __restrict__ Z, const int* __restrict__ seg,
                       float* __restrict__ POOL, float* __restrict__ CNT, int total)
{
    int i = blockIdx.x*blockDim.x + threadIdx.x;
    if (i >= total) return;
    int h = i % HID, n = i / HID;
    int s = seg[n];
    atomicAdd(&POOL[s*HID + h], Z[i]);
    if (h == 0) atomicAdd(&CNT[s], 1.f);
}

__global__ __launch_bounds__(64)
void out_k(const float* __restrict__ POOL, const float* __restrict__ CNT,
           const float* __restrict__ outW, const float* __restrict__ outb,
           float* __restrict__ out)
{
    int c = threadIdx.x;
    float cnt = fmaxf(CNT[c], 1.f);
    float s = 0.f;
    #pragma unroll 4
    for (int h=0;h<HID;h++) s += POOL[c*HID + h]*outW[h];
    out[c] = s/cnt + outb[0];
}

extern "C" void kernel_launch(void* const* d_in, const int* in_sizes, int n_in,
                              void* d_out, int out_size, void* d_ws, size_t ws_size,
                              hipStream_t stream)
{
    const float* atom_fea = (const float*)d_in[0];
    const float* nbr_fea  = (const float*)d_in[1];
    const int*   nbr_idx  = (const int*)d_in[2];
    const int*   site_seg = (const int*)d_in[3];
    const float* emb_W = (const float*)d_in[4];
    const float* emb_b = (const float*)d_in[5];
    const float* fcW   = (const float*)d_in[6];
    const float* fcb   = (const float*)d_in[7];
    const float* bn1_g = (const float*)d_in[8];
    const float* bn1_b = (const float*)d_in[9];
    const float* bn2_g = (const float*)d_in[10];
    const float* bn2_b = (const float*)d_in[11];
    const float* eW    = (const float*)d_in[12];
    const float* eb    = (const float*)d_in[13];
    const float* bne_g = (const float*)d_in[14];
    const float* bne_b = (const float*)d_in[15];
    const float* W3    = (const float*)d_in[16];
    const float* b3    = (const float*)d_in[17];
    const float* bn3_g = (const float*)d_in[18];
    const float* bn3_b = (const float*)d_in[19];
    const float* fc1W  = (const float*)d_in[20];
    const float* fc1b  = (const float*)d_in[21];
    const float* outW  = (const float*)d_in[22];
    const float* outb  = (const float*)d_in[23];

    // workspace layout (floats), all offsets 16-float aligned; total ~12.48M floats (~50 MB)
    float* ws   = (float*)d_ws;
    float* X    = ws;                    // 128000
    float* E    = ws + 128000;           // 984000
    float* TOT  = ws + 1112000;          // 24000*176 = 4224000
    float* HB   = ws + 5336000;          // 24000*256 = 6144000
    float* BASE = ws + 11480000;         // 256000
    float* TB   = ws + 11736000;         // 128000
    float* ST   = ws + 11864000;         // 2048
    float* WA   = ws + 11866048;         // 3*256*176 = 135168
    float* WPQ  = ws + 12001216;         // 3*256*112 = 86016
    float* BIAS = ws + 12087232;         // 768 (+pad)
    float* XS   = ws + 12088000;         // 128000
    float* Z    = ws + 12216000;         // 256000
    float* POOL = ws + 12472000;         // 8192
    float* CNT  = POOL + 8192;           // 64

    float *S1A=ST+0,    *S2A=ST+256,  *sA=ST+512,  *tA=ST+768;
    float *S13=ST+1024, *S23=ST+1152, *s3=ST+1280, *t3=ST+1408;
    float *S12=ST+1536, *S22=ST+1600, *s2=ST+1664, *t2=ST+1728;

    // pack weights/bias for all layers (one dispatch)
    {
        int tot = NCONV*256*LWA + NCONV*256*LWB + NCONV*256;
        pack_all<<<(tot+255)/256, 256, 0, stream>>>(fcW, eW, W3, fcb, eb, WA, WPQ, BIAS);
    }
    // embedding: X = atom_fea @ emb_W^T + emb_b
    gemm_tn<0><<<(N_ATOM+BM-1)/BM, 256, 0, stream>>>(atom_fea, OFEA, N_ATOM,
                                                     emb_W, OFEA, OFEA, AF, emb_b, X, AF);
    hipMemcpyAsync(E, nbr_fea, (size_t)NM*BFEA*sizeof(float),
                   hipMemcpyDeviceToDevice, stream);

    for (int i = 0; i < NCONV; i++){
        const float* g1 = bn1_g + i*O1, *b1 = bn1_b + i*O1;
        const float* g2 = bn2_g + i*AF, *b2 = bn2_b + i*AF;
        const float* ge = bne_g + i*OE, *be = bne_b + i*OE;
        const float* W3_i = W3 + (size_t)i*O1*K3;
        const float* b3_i = b3 + i*O1;
        const float* g3 = bn3_g + i*O1, *b3b = bn3_b + i*O1;

        hipMemsetAsync(ST, 0, 2048*sizeof(float), stream);
        gather_tot<<<(NM*LDT+255)/256, 256, 0, stream>>>(TOT, X, E, nbr_idx, NM*LDT);

        // GEMM_A: [h | he] = tot @ [fcW|eW]^T + [fcb|eb]   (O=210 in 2 col-tiles)
        {
            dim3 g((NM+127)/128, 2);
            gemm_f<<<g, 256, 0, stream>>>(TOT, LDT, NM, WA + (size_t)i*256*LWA, LWA,
                                          KA_T, BIAS + i*256, HB, LDH);
        }
        bn_stats_cols<<<256, 256, 0, stream>>>(HB, LDH, NM, O1+OE, S1A, S2A);
        bn_finalize2<<<1, 256, 0, stream>>>(S1A, S2A, 1.f/NM, g1, b1, ge, be, sA, tA);
        two_body_k<<<N_ATOM, 64, 0, stream>>>(HB, sA, tA, TB);
        e_update_k<<<(NM*BFEA+255)/256, 256, 0, stream>>>(E, HB, sA, tA, NM*BFEA);

        // GEMM_B: [P | Q] from tot[:,64:169] @ WPQ^T (overwrites HB; h/he consumed)
        {
            dim3 g((NM+127)/128, 2);
            gemm_f<<<g, 256, 0, stream>>>(TOT + AF, LDT, NM, WPQ + (size_t)i*256*LWB, LWB,
                                          KB_T, nullptr, HB, LDH);
        }
        // BASE = X @ Wa^T + b3
        gemm_tn<0><<<(N_ATOM+BM-1)/BM, 256, 0, stream>>>(X, AF, N_ATOM, W3_i, K3, AF, O1,
                                                         b3_i, BASE, O1);
        bn3_stats<<<(N_ATOM+15)/16, 128, 0, stream>>>(BASE, HB, N_ATOM, S13, S23);
        bn_finalize<<<1, 128, 0, stream>>>(S13, S23, 1.f/((float)NM*MNBR), g3, b3b, O1, s3, t3);
        three_body_k<<<N_ATOM, 64, 0, stream>>>(BASE, HB, s3, t3, TB);

        bn_stats_cols<<<128, 64, 0, stream>>>(TB, AF, N_ATOM, AF, S12, S22);
        bn_finalize<<<1, 64, 0, stream>>>(S12, S22, 1.f/N_ATOM, g2, b2, AF, s2, t2);
        x_update_k<<<(N_ATOM*AF+255)/256, 256, 0, stream>>>(X, TB, s2, t2, N_ATOM*AF);
    }

    // head
    softplus_k<<<(N_ATOM*AF+255)/256, 256, 0, stream>>>(X, XS, N_ATOM*AF);
    gemm_tn<1><<<(N_ATOM+BM-1)/BM, 256, 0, stream>>>(XS, AF, N_ATOM, fc1W, AF, AF, HID,
                                                     fc1b, Z, HID);
    hipMemsetAsync(POOL, 0, (8192+64)*sizeof(float), stream);
    pool_k<<<(N_ATOM*HID+255)/256, 256, 0, stream>>>(Z, site_seg, POOL, CNT, N_ATOM*HID);
    out_k<<<1, 64, 0, stream>>>(POOL, CNT, outW, outb, (float*)d_out);
}

// Round 4
// 533.988 us; speedup vs baseline: 2.5373x; 1.4442x over previous
//
#include <hip/hip_runtime.h>
#include <hip/hip_bf16.h>

// Problem constants
#define N_ATOM 2000
#define MNBR   12
#define OFEA   92
#define AF     64
#define BFEA   41
#define K1     169   // 2A+B
#define O1     128
#define OE     82
#define K3     274   // 3A+2B
#define NM     24000
#define NCONV  3
#define HID    128
#define NCRY   64
#define EPS_BN 1e-5f

#define LDA_T  192   // bf16 TOT leading dim (169 padded to 192)
#define LDH    512   // REST leading dim: [h(0..127)|he(128..209)|pad|P(256..383)|Q(384..511)]
#define LDSW   88    // LDS row pitch (ushorts) for MFMA tiles (16B aligned, conflict-friendly)

typedef __bf16 bf16x8 __attribute__((ext_vector_type(8)));
typedef float  f32x4  __attribute__((ext_vector_type(4)));

__device__ __forceinline__ float sigmoidf_(float x){ return 1.f/(1.f+__expf(-x)); }
__device__ __forceinline__ float softplusf_(float x){
    return fmaxf(x,0.f) + __logf(1.f + __expf(-fabsf(x)));
}

// ================= bf16 MFMA GEMM: C[r,c] = bias[c] + sum_k A[r,k]*W[c,k]
// A: 24000x192 bf16, W: 512x192 bf16, C: 24000x512 fp32. Block tile 128x128,
// 4 waves, wave tile 64x64 (4x4 of 16x16x32). K staged in 3 chunks of 64.
__global__ __launch_bounds__(256)
void gemm_bf16(const __hip_bfloat16* __restrict__ A,
               const __hip_bfloat16* __restrict__ W,
               const float* __restrict__ bias,
               float* __restrict__ C)
{
    __shared__ unsigned short As[128][LDSW];
    __shared__ unsigned short Ws[128][LDSW];
    const int tid  = threadIdx.x;
    const int row0 = blockIdx.x * 128;
    const int col0 = blockIdx.y * 128;
    const int w    = tid >> 6;        // wave 0..3
    const int l    = tid & 63;
    const int wm   = w >> 1, wn = w & 1;
    const int lrow = l & 15;
    const int quad = l >> 4;

    f32x4 acc[4][4];
    #pragma unroll
    for (int i=0;i<4;i++)
        #pragma unroll
        for (int j=0;j<4;j++) acc[i][j] = (f32x4){0.f,0.f,0.f,0.f};

    for (int it = 0; it < 3; ++it){
        const int k0 = it * 64;
        if (it) __syncthreads();
        // stage A tile (128 rows x 64 k) and W tile (128 cols x 64 k)
        #pragma unroll
        for (int j = 0; j < 4; ++j){
            int e  = tid + j*256;          // 0..1023 (uint4 units of 8 bf16)
            int r  = e >> 3;
            int kk = (e & 7) << 3;
            int grow = row0 + r;
            uint4 va = make_uint4(0,0,0,0);
            if (grow < NM)
                va = *(const uint4*)(A + (size_t)grow*LDA_T + k0 + kk);
            *(uint4*)(&As[r][kk]) = va;
            uint4 vw = *(const uint4*)(W + (size_t)(col0 + r)*LDA_T + k0 + kk);
            *(uint4*)(&Ws[r][kk]) = vw;
        }
        __syncthreads();
        #pragma unroll
        for (int ks = 0; ks < 2; ++ks){
            int koff = ks*32 + quad*8;
            bf16x8 a_[4], b_[4];
            #pragma unroll
            for (int mi=0;mi<4;mi++)
                a_[mi] = *(const bf16x8*)(&As[wm*64 + mi*16 + lrow][koff]);
            #pragma unroll
            for (int ni=0;ni<4;ni++)
                b_[ni] = *(const bf16x8*)(&Ws[wn*64 + ni*16 + lrow][koff]);
            #pragma unroll
            for (int mi=0;mi<4;mi++)
                #pragma unroll
                for (int ni=0;ni<4;ni++)
                    acc[mi][ni] = __builtin_amdgcn_mfma_f32_16x16x32_bf16(
                        a_[mi], b_[ni], acc[mi][ni], 0, 0, 0);
        }
    }
    // epilogue: C/D layout col=lane&15, row=quad*4+reg
    #pragma unroll
    for (int ni=0;ni<4;ni++){
        int col = col0 + wn*64 + ni*16 + lrow;
        float bv = bias[col];
        #pragma unroll
        for (int mi=0;mi<4;mi++){
            int rbase = row0 + wm*64 + mi*16 + quad*4;
            #pragma unroll
            for (int reg=0;reg<4;reg++){
                int grow = rbase + reg;
                if (grow < NM)
                    C[(size_t)grow*LDH + col] = acc[mi][ni][reg] + bv;
            }
        }
    }
}

// ================= small fp32 GEMM (embedding / BASE / head)
#define BM 64
#define BN 128
#define BK 32
template<int EPI, int SPIN>   // EPI: softplus on output; SPIN: softplus on A-load
__global__ __launch_bounds__(256)
void gemm_tn(const float* __restrict__ T, int ldt, int R,
             const float* __restrict__ W, int ldw, int K, int O,
             const float* __restrict__ bias,
             float* __restrict__ C, int ldc)
{
    __shared__ float Ts[BM][BK+1];
    __shared__ float Ws2[BN][BK+1];
    const int tid = threadIdx.x;
    const int row0 = blockIdx.x * BM;
    const int tx = tid % 16;
    const int ty = tid / 16;
    float acc[4][8];
    #pragma unroll
    for (int i=0;i<4;i++)
        #pragma unroll
        for (int j=0;j<8;j++) acc[i][j]=0.f;

    for (int k0 = 0; k0 < K; k0 += BK) {
        #pragma unroll
        for (int i=0;i<(BM*BK)/256;i++){
            int e = tid + i*256;
            int r = e / BK, k = e % BK;
            int gr = row0 + r, gk = k0 + k;
            float v = 0.f;
            if (gr < R && gk < K){
                v = T[(size_t)gr*ldt + gk];
                if (SPIN) v = softplusf_(v);
            }
            Ts[r][k] = v;
        }
        #pragma unroll
        for (int i=0;i<(BN*BK)/256;i++){
            int e = tid + i*256;
            int r = e / BK, k = e % BK;
            int gk = k0 + k;
            Ws2[r][k] = (r < O && gk < K) ? W[(size_t)r*ldw + gk] : 0.f;
        }
        __syncthreads();
        #pragma unroll
        for (int k=0;k<BK;k++){
            float a_[4], b_[8];
            #pragma unroll
            for (int i=0;i<4;i++) a_[i] = Ts[ty*4+i][k];
            #pragma unroll
            for (int j=0;j<8;j++) b_[j] = Ws2[tx + j*16][k];
            #pragma unroll
            for (int i=0;i<4;i++)
                #pragma unroll
                for (int j=0;j<8;j++)
                    acc[i][j] += a_[i]*b_[j];
        }
        __syncthreads();
    }
    #pragma unroll
    for (int i=0;i<4;i++){
        int gr = row0 + ty*4 + i;
        if (gr >= R) continue;
        #pragma unroll
        for (int j=0;j<8;j++){
            int gc = tx + j*16;
            if (gc >= O) continue;
            float v = acc[i][j] + (bias ? bias[gc] : 0.f);
            if (EPI==1) v = softplusf_(v);
            C[(size_t)gr*ldc + gc] = v;
        }
    }
}

// ================= pack weights (bf16) + bias (fp32) for all layers
// WALL[l][c][k]: c<128: fcW; 128..209: eW; 256..383: P=[0|Wj|Wij|0]; 384..511: Q=[0|Wl|Wil|0]
__global__ void pack_all(const float* __restrict__ fcW, const float* __restrict__ eW,
                         const float* __restrict__ W3, const float* __restrict__ fcb,
                         const float* __restrict__ eb,
                         __hip_bfloat16* __restrict__ WALL, float* __restrict__ BIAS)
{
    int i = blockIdx.x*blockDim.x + threadIdx.x;
    const int nW = NCONV*512*LDA_T;
    if (i < nW){
        int l = i/(512*LDA_T), rem = i%(512*LDA_T);
        int c = rem/LDA_T, k = rem%LDA_T;
        float v = 0.f;
        if (c < O1){
            if (k < K1) v = fcW[((size_t)l*O1 + c)*K1 + k];
        } else if (c < O1+OE){
            if (k < K1) v = eW[((size_t)l*OE + (c-O1))*K1 + k];
        } else if (c >= 256 && c < 384){
            int o = c - 256;
            const float* W3l = W3 + (size_t)l*O1*K3;
            if (k >= AF && k < 2*AF)           v = W3l[(size_t)o*K3 + k];          // Wj
            else if (k >= 2*AF && k < K1)      v = W3l[(size_t)o*K3 + 192 + (k-128)]; // Wij
        } else if (c >= 384){
            int o = c - 384;
            const float* W3l = W3 + (size_t)l*O1*K3;
            if (k >= AF && k < 2*AF)           v = W3l[(size_t)o*K3 + k + AF];     // Wl
            else if (k >= 2*AF && k < K1)      v = W3l[(size_t)o*K3 + 233 + (k-128)]; // Wil
        }
        WALL[i] = __float2bfloat16(v);
    } else if (i < nW + NCONV*512){
        int m = i - nW;
        int l = m/512, c = m%512;
        float v = 0.f;
        if (c < O1)         v = fcb[l*O1 + c];
        else if (c < O1+OE) v = eb[l*OE + (c-O1)];
        BIAS[m] = v;
    }
}

// ================= tot (bf16): [x | xn | e | 0], lda=192
__global__ void gather_b(__hip_bfloat16* __restrict__ TOT, const float* __restrict__ X,
                         const float* __restrict__ E, const int* __restrict__ idx,
                         int total)
{
    int i = blockIdx.x*blockDim.x + threadIdx.x;
    if (i >= total) return;
    int f = i % LDA_T;
    int r = i / LDA_T;
    int n = r / MNBR;
    float v = 0.f;
    if (f < AF)            v = X[n*AF + f];
    else if (f < 2*AF)     v = X[idx[r]*AF + (f-AF)];
    else if (f < K1)       v = E[r*BFEA + (f-2*AF)];
    TOT[i] = __float2bfloat16(v);
}

// ================= fused stats: h/he column sums (210 ch) + closed-form BN3 sums
// block = 8 atoms (96 rows); S1A/S2A: 210 ch, S13/S23: 128 ch
__global__ __launch_bounds__(256)
void stats_all(const float* __restrict__ REST, const float* __restrict__ BASE,
               float* __restrict__ S1A, float* __restrict__ S2A,
               float* __restrict__ S13, float* __restrict__ S23)
{
    const int tid = threadIdx.x;
    const int n0 = blockIdx.x * 8;
    const int r0 = n0 * MNBR;
    if (tid < O1+OE){
        float s1 = 0.f, s2 = 0.f;
        for (int j = 0; j < 8*MNBR; ++j){
            float v = REST[(size_t)(r0+j)*LDH + tid];
            s1 += v; s2 += v*v;
        }
        atomicAdd(&S1A[tid], s1);
        atomicAdd(&S2A[tid], s2);
    }
    if (tid < O1){
        float s1 = 0.f, s2 = 0.f;
        for (int a = 0; a < 8; ++a){
            int n = n0 + a;
            float B = BASE[(size_t)n*O1 + tid];
            float sp=0.f, spp=0.f, sq=0.f, sqq=0.f;
            #pragma unroll
            for (int m=0;m<MNBR;m++){
                const float* row = REST + (size_t)(n*MNBR+m)*LDH;
                float p = row[256 + tid];
                float q = row[384 + tid];
                sp += p; spp += p*p; sq += q; sqq += q*q;
            }
            s1 += 144.f*B + 12.f*(sp+sq);
            s2 += 144.f*B*B + 12.f*(spp+sqq) + 24.f*B*(sp+sq) + 2.f*sp*sq;
        }
        atomicAdd(&S13[tid], s1);
        atomicAdd(&S23[tid], s2);
    }
}

// ================= fused consumer (block = atom, 64 threads):
// inline BN finalize; two-body + three-body -> TB; edge update -> E
__global__ __launch_bounds__(64)
void consumer_k(const float* __restrict__ REST, const float* __restrict__ BASE,
                const float* __restrict__ S1A, const float* __restrict__ S2A,
                const float* __restrict__ S13, const float* __restrict__ S23,
                const float* __restrict__ g1, const float* __restrict__ b1,
                const float* __restrict__ ge, const float* __restrict__ be,
                const float* __restrict__ g3, const float* __restrict__ b3b,
                float* __restrict__ TB, float* __restrict__ E)
{
    __shared__ float sA[O1+OE], tA[O1+OE], s3a[O1], t3a[O1];
    const int n = blockIdx.x;
    const int t = threadIdx.x;
    const float invA = 1.f/(float)NM;
    const float inv3 = 1.f/((float)NM*MNBR);
    for (int c = t; c < O1+OE; c += 64){
        float mean = S1A[c]*invA;
        float var  = fmaxf(S2A[c]*invA - mean*mean, 0.f);
        float g = (c < O1) ? g1[c] : ge[c-O1];
        float b = (c < O1) ? b1[c] : be[c-O1];
        float sc = g * rsqrtf(var + EPS_BN);
        sA[c] = sc; tA[c] = b - sc*mean;
    }
    for (int c = t; c < O1; c += 64){
        float mean = S13[c]*inv3;
        float var  = fmaxf(S23[c]*inv3 - mean*mean, 0.f);
        float sc = g3[c] * rsqrtf(var + EPS_BN);
        s3a[c] = sc; t3a[c] = b3b[c] - sc*mean;
    }
    __syncthreads();

    const int a = t;
    float sa = s3a[a], sb = s3a[AF+a];
    float Ba = sa*BASE[(size_t)n*O1 + a]      + t3a[a];
    float Bb = sb*BASE[(size_t)n*O1 + AF + a] + t3a[AF+a];
    float Pa[MNBR], Pb[MNBR], Qa[MNBR], Qb[MNBR];
    float sha = sA[a], tha = tA[a], shb = sA[AF+a], thb = tA[AF+a];
    float acc2 = 0.f;
    #pragma unroll
    for (int m=0;m<MNBR;m++){
        const float* row = REST + (size_t)(n*MNBR+m)*LDH;
        acc2 += sigmoidf_(sha*row[a]+tha) * softplusf_(shb*row[AF+a]+thb);
        Pa[m] = sa*row[256+a];    Pb[m] = sb*row[320+a];
        Qa[m] = sa*row[384+a];    Qb[m] = sb*row[448+a];
    }
    float acc3 = 0.f;
    #pragma unroll
    for (int m=0;m<MNBR;m++){
        float ua = Ba + Pa[m], ub = Bb + Pb[m];
        #pragma unroll
        for (int l2=0;l2<MNBR;l2++)
            acc3 += sigmoidf_(ua + Qa[l2]) * softplusf_(ub + Qb[l2]);
    }
    TB[(size_t)n*AF + a] = acc2 + acc3;

    // edge update: 12*41 elements
    for (int idx = t; idx < MNBR*BFEA; idx += 64){
        int m = idx / BFEA, b = idx % BFEA;
        const float* row = REST + (size_t)(n*MNBR+m)*LDH;
        float u = sA[O1+b]*row[O1+b] + tA[O1+b];
        float v = sA[O1+BFEA+b]*row[O1+BFEA+b] + tA[O1+BFEA+b];
        E[(size_t)(n*MNBR+m)*BFEA + b] += sigmoidf_(u) * softplusf_(v);
    }
}

// ================= per-column sum/sumsq (for TB)
__global__ void bn_stats_cols(const float* __restrict__ C, int ld, int R, int O,
                              float* __restrict__ S1, float* __restrict__ S2)
{
    int t = threadIdx.x;
    if (t >= O) return;
    float s1 = 0.f, s2 = 0.f;
    for (int r = blockIdx.x; r < R; r += gridDim.x){
        float v = C[(size_t)r*ld + t];
        s1 += v; s2 += v*v;
    }
    atomicAdd(&S1[t], s1);
    atomicAdd(&S2[t], s2);
}

// ================= x = softplus(x + bn2(TB)), inline finalize
__global__ void x_update_k(float* __restrict__ X, const float* __restrict__ TB,
                           const float* __restrict__ S12, const float* __restrict__ S22,
                           const float* __restrict__ g2, const float* __restrict__ b2,
                           int total)
{
    int i = blockIdx.x*blockDim.x + threadIdx.x;
    if (i >= total) return;
    int a = i & (AF-1);
    float mean = S12[a]*(1.f/N_ATOM);
    float var  = fmaxf(S22[a]*(1.f/N_ATOM) - mean*mean, 0.f);
    float sc = g2[a]*rsqrtf(var + EPS_BN);
    X[i] = softplusf_(X[i] + sc*TB[i] + (b2[a] - sc*mean));
}

// ================= pooled mean per crystal + final dot (binary search on sorted seg)
__global__ __launch_bounds__(128)
void pool_out_k(const float* __restrict__ Z, const int* __restrict__ seg,
                const float* __restrict__ outW, const float* __restrict__ outb,
                float* __restrict__ out)
{
    __shared__ float red[128];
    const int c = blockIdx.x;
    const int h = threadIdx.x;
    int l0, l1;
    {   // lower_bound(c), lower_bound(c+1)
        int l=0, r=N_ATOM;
        while (l<r){ int m=(l+r)>>1; if (seg[m] < c) l=m+1; else r=m; }
        l0 = l;
        l=l0; r=N_ATOM;
        while (l<r){ int m=(l+r)>>1; if (seg[m] < c+1) l=m+1; else r=m; }
        l1 = l;
    }
    float s = 0.f;
    for (int n = l0; n < l1; ++n) s += Z[(size_t)n*HID + h];
    float cnt = fmaxf((float)(l1-l0), 1.f);
    red[h] = (s/cnt) * outW[h];
    __syncthreads();
    for (int off=64; off>0; off>>=1){
        if (h < off) red[h] += red[h+off];
        __syncthreads();
    }
    if (h == 0) out[c] = red[0] + outb[0];
}

extern "C" void kernel_launch(void* const* d_in, const int* in_sizes, int n_in,
                              void* d_out, int out_size, void* d_ws, size_t ws_size,
                              hipStream_t stream)
{
    const float* atom_fea = (const float*)d_in[0];
    const float* nbr_fea  = (const float*)d_in[1];
    const int*   nbr_idx  = (const int*)d_in[2];
    const int*   site_seg = (const int*)d_in[3];
    const float* emb_W = (const float*)d_in[4];
    const float* emb_b = (const float*)d_in[5];
    const float* fcW   = (const float*)d_in[6];
    const float* fcb   = (const float*)d_in[7];
    const float* bn1_g = (const float*)d_in[8];
    const float* bn1_b = (const float*)d_in[9];
    const float* bn2_g = (const float*)d_in[10];
    const float* bn2_b = (const float*)d_in[11];
    const float* eW    = (const float*)d_in[12];
    const float* eb    = (const float*)d_in[13];
    const float* bne_g = (const float*)d_in[14];
    const float* bne_b = (const float*)d_in[15];
    const float* W3    = (const float*)d_in[16];
    const float* b3    = (const float*)d_in[17];
    const float* bn3_g = (const float*)d_in[18];
    const float* bn3_b = (const float*)d_in[19];
    const float* fc1W  = (const float*)d_in[20];
    const float* fc1b  = (const float*)d_in[21];
    const float* outW  = (const float*)d_in[22];
    const float* outb  = (const float*)d_in[23];

    // workspace layout (float units), ~66 MB total
    float* ws   = (float*)d_ws;
    float* X    = ws;                        // 128000
    float* E    = ws + 128000;               // 984000
    __hip_bfloat16* TOT = (__hip_bfloat16*)(ws + 1112000);   // 24000*192 bf16 = 2304000 fl
    float* REST = ws + 3416000;              // 24000*512 = 12288000
    float* BASE = ws + 15704000;             // 256000
    float* TB   = ws + 15960000;             // 128000
    float* ST   = ws + 16088000;             // 3*2048
    __hip_bfloat16* WALL = (__hip_bfloat16*)(ws + 16094144); // 3*512*192 bf16 = 147456 fl
    float* BIAS = ws + 16241600;             // 1536 (+pad)
    float* Z    = ws + 16243200;             // 256000

    // one pack + one stats-zero for all layers
    {
        int tot = NCONV*512*LDA_T + NCONV*512;
        pack_all<<<(tot+255)/256, 256, 0, stream>>>(fcW, eW, W3, fcb, eb, WALL, BIAS);
    }
    hipMemsetAsync(ST, 0, NCONV*2048*sizeof(float), stream);
    gemm_tn<0,0><<<(N_ATOM+BM-1)/BM, 256, 0, stream>>>(atom_fea, OFEA, N_ATOM,
                                                       emb_W, OFEA, OFEA, AF, emb_b, X, AF);
    hipMemcpyAsync(E, nbr_fea, (size_t)NM*BFEA*sizeof(float),
                   hipMemcpyDeviceToDevice, stream);

    for (int i = 0; i < NCONV; i++){
        const float* g1 = bn1_g + i*O1, *b1 = bn1_b + i*O1;
        const float* g2 = bn2_g + i*AF, *b2 = bn2_b + i*AF;
        const float* ge = bne_g + i*OE, *be = bne_b + i*OE;
        const float* W3_i = W3 + (size_t)i*O1*K3;
        const float* b3_i = b3 + i*O1;
        const float* g3 = bn3_g + i*O1, *b3b = bn3_b + i*O1;
        float* STL = ST + i*2048;
        float *S1A=STL, *S2A=STL+256, *S13=STL+512, *S23=STL+640, *S12=STL+768, *S22=STL+832;

        gather_b<<<(NM*LDA_T+255)/256, 256, 0, stream>>>(TOT, X, E, nbr_idx, NM*LDA_T);

        // one bf16 MFMA GEMM: [h | he | P | Q] (N=512, K=192)
        {
            dim3 g((NM+127)/128, 4);
            gemm_bf16<<<g, 256, 0, stream>>>(TOT, WALL + (size_t)i*512*LDA_T,
                                             BIAS + i*512, REST);
        }
        // BASE = X @ Wa^T + b3 (fp32, small)
        gemm_tn<0,0><<<(N_ATOM+BM-1)/BM, 256, 0, stream>>>(X, AF, N_ATOM, W3_i, K3, AF, O1,
                                                           b3_i, BASE, O1);
        stats_all<<<N_ATOM/8, 256, 0, stream>>>(REST, BASE, S1A, S2A, S13, S23);
        consumer_k<<<N_ATOM, 64, 0, stream>>>(REST, BASE, S1A, S2A, S13, S23,
                                              g1, b1, ge, be, g3, b3b, TB, E);
        bn_stats_cols<<<128, 64, 0, stream>>>(TB, AF, N_ATOM, AF, S12, S22);
        x_update_k<<<(N_ATOM*AF+255)/256, 256, 0, stream>>>(X, TB, S12, S22, g2, b2,
                                                            N_ATOM*AF);
    }

    // head: Z = softplus(softplus(X) @ fc1W^T + fc1b); pooled mean; out
    gemm_tn<1,1><<<(N_ATOM+BM-1)/BM, 256, 0, stream>>>(X, AF, N_ATOM, fc1W, AF, AF, HID,
                                                       fc1b, Z, HID);
    pool_out_k<<<NCRY, 128, 0, stream>>>(Z, site_seg, outW, outb, (float*)d_out);
}

// Round 5
// 514.749 us; speedup vs baseline: 2.6322x; 1.0374x over previous
//
#include <hip/hip_runtime.h>
#include <hip/hip_bf16.h>

// Problem constants
#define N_ATOM 2000
#define MNBR   12
#define OFEA   92
#define AF     64
#define BFEA   41
#define K1     169   // 2A+B
#define O1     128
#define OE     82
#define K3     274   // 3A+2B
#define NM     24000
#define NCONV  3
#define HID    128
#define NCRY   64
#define EPS_BN 1e-5f

#define LDA_T  192   // bf16 TOT leading dim (169 padded to 192)
#define LDH    512   // REST: [h(0..127)|he(128..209)|pad|P'(256..383)|Q'(384..511)]
#define LDSW   88    // LDS row pitch (ushorts) for MFMA tiles

typedef __bf16 bf16x8 __attribute__((ext_vector_type(8)));
typedef float  f32x4  __attribute__((ext_vector_type(4)));

__device__ __forceinline__ float sigmoidf_(float x){ return 1.f/(1.f+__expf(-x)); }
__device__ __forceinline__ float softplusf_(float x){
    return fmaxf(x,0.f) + __logf(1.f + __expf(-fabsf(x)));
}

// ================= bf16 MFMA GEMM: C[r,c] = bias[c] + sum_k A[r,k]*W[c,k]
__global__ __launch_bounds__(256)
void gemm_bf16(const __hip_bfloat16* __restrict__ A,
               const __hip_bfloat16* __restrict__ W,
               const float* __restrict__ bias,
               float* __restrict__ C)
{
    __shared__ unsigned short As[128][LDSW];
    __shared__ unsigned short Ws[128][LDSW];
    const int tid  = threadIdx.x;
    const int row0 = blockIdx.x * 128;
    const int col0 = blockIdx.y * 128;
    const int w    = tid >> 6;
    const int l    = tid & 63;
    const int wm   = w >> 1, wn = w & 1;
    const int lrow = l & 15;
    const int quad = l >> 4;

    f32x4 acc[4][4];
    #pragma unroll
    for (int i=0;i<4;i++)
        #pragma unroll
        for (int j=0;j<4;j++) acc[i][j] = (f32x4){0.f,0.f,0.f,0.f};

    for (int it = 0; it < 3; ++it){
        const int k0 = it * 64;
        if (it) __syncthreads();
        #pragma unroll
        for (int j = 0; j < 4; ++j){
            int e  = tid + j*256;
            int r  = e >> 3;
            int kk = (e & 7) << 3;
            int grow = row0 + r;
            uint4 va = make_uint4(0,0,0,0);
            if (grow < NM)
                va = *(const uint4*)(A + (size_t)grow*LDA_T + k0 + kk);
            *(uint4*)(&As[r][kk]) = va;
            uint4 vw = *(const uint4*)(W + (size_t)(col0 + r)*LDA_T + k0 + kk);
            *(uint4*)(&Ws[r][kk]) = vw;
        }
        __syncthreads();
        #pragma unroll
        for (int ks = 0; ks < 2; ++ks){
            int koff = ks*32 + quad*8;
            bf16x8 a_[4], b_[4];
            #pragma unroll
            for (int mi=0;mi<4;mi++)
                a_[mi] = *(const bf16x8*)(&As[wm*64 + mi*16 + lrow][koff]);
            #pragma unroll
            for (int ni=0;ni<4;ni++)
                b_[ni] = *(const bf16x8*)(&Ws[wn*64 + ni*16 + lrow][koff]);
            #pragma unroll
            for (int mi=0;mi<4;mi++)
                #pragma unroll
                for (int ni=0;ni<4;ni++)
                    acc[mi][ni] = __builtin_amdgcn_mfma_f32_16x16x32_bf16(
                        a_[mi], b_[ni], acc[mi][ni], 0, 0, 0);
        }
    }
    #pragma unroll
    for (int ni=0;ni<4;ni++){
        int col = col0 + wn*64 + ni*16 + lrow;
        float bv = bias[col];
        #pragma unroll
        for (int mi=0;mi<4;mi++){
            int rbase = row0 + wm*64 + mi*16 + quad*4;
            #pragma unroll
            for (int reg=0;reg<4;reg++){
                int grow = rbase + reg;
                if (grow < NM)
                    C[(size_t)grow*LDH + col] = acc[mi][ni][reg] + bv;
            }
        }
    }
}

// ================= small fp32 GEMM (embedding / head)
#define BM 64
#define BN 128
#define BK 32
template<int EPI, int SPIN>
__global__ __launch_bounds__(256)
void gemm_tn(const float* __restrict__ T, int ldt, int R,
             const float* __restrict__ W, int ldw, int K, int O,
             const float* __restrict__ bias,
             float* __restrict__ C, int ldc)
{
    __shared__ float Ts[BM][BK+1];
    __shared__ float Ws2[BN][BK+1];
    const int tid = threadIdx.x;
    const int row0 = blockIdx.x * BM;
    const int tx = tid % 16;
    const int ty = tid / 16;
    float acc[4][8];
    #pragma unroll
    for (int i=0;i<4;i++)
        #pragma unroll
        for (int j=0;j<8;j++) acc[i][j]=0.f;

    for (int k0 = 0; k0 < K; k0 += BK) {
        #pragma unroll
        for (int i=0;i<(BM*BK)/256;i++){
            int e = tid + i*256;
            int r = e / BK, k = e % BK;
            int gr = row0 + r, gk = k0 + k;
            float v = 0.f;
            if (gr < R && gk < K){
                v = T[(size_t)gr*ldt + gk];
                if (SPIN) v = softplusf_(v);
            }
            Ts[r][k] = v;
        }
        #pragma unroll
        for (int i=0;i<(BN*BK)/256;i++){
            int e = tid + i*256;
            int r = e / BK, k = e % BK;
            int gk = k0 + k;
            Ws2[r][k] = (r < O && gk < K) ? W[(size_t)r*ldw + gk] : 0.f;
        }
        __syncthreads();
        #pragma unroll
        for (int k=0;k<BK;k++){
            float a_[4], b_[8];
            #pragma unroll
            for (int i=0;i<4;i++) a_[i] = Ts[ty*4+i][k];
            #pragma unroll
            for (int j=0;j<8;j++) b_[j] = Ws2[tx + j*16][k];
            #pragma unroll
            for (int i=0;i<4;i++)
                #pragma unroll
                for (int j=0;j<8;j++)
                    acc[i][j] += a_[i]*b_[j];
        }
        __syncthreads();
    }
    #pragma unroll
    for (int i=0;i<4;i++){
        int gr = row0 + ty*4 + i;
        if (gr >= R) continue;
        #pragma unroll
        for (int j=0;j<8;j++){
            int gc = tx + j*16;
            if (gc >= O) continue;
            float v = acc[i][j] + (bias ? bias[gc] : 0.f);
            if (EPI==1) v = softplusf_(v);
            C[(size_t)gr*ldc + gc] = v;
        }
    }
}

// ================= pack weights (bf16) + bias (fp32).
// WALL[l][c][k]: c<128: fcW; 128..209: eW;
// 256..383: P' = [Wa/2 | Wj | Wij | 0]; 384..511: Q' = [Wa/2 | Wl | Wil | 0]
// BIAS: [fcb | eb | pad | b3/2 | b3/2]
__global__ void pack_all(const float* __restrict__ fcW, const float* __restrict__ eW,
                         const float* __restrict__ W3, const float* __restrict__ fcb,
                         const float* __restrict__ eb, const float* __restrict__ b3,
                         __hip_bfloat16* __restrict__ WALL, float* __restrict__ BIAS)
{
    int i = blockIdx.x*blockDim.x + threadIdx.x;
    const int nW = NCONV*512*LDA_T;
    if (i < nW){
        int l = i/(512*LDA_T), rem = i%(512*LDA_T);
        int c = rem/LDA_T, k = rem%LDA_T;
        float v = 0.f;
        if (c < O1){
            if (k < K1) v = fcW[((size_t)l*O1 + c)*K1 + k];
        } else if (c < O1+OE){
            if (k < K1) v = eW[((size_t)l*OE + (c-O1))*K1 + k];
        } else if (c >= 256 && c < 384){
            int o = c - 256;
            const float* W3l = W3 + (size_t)l*O1*K3;
            if (k < AF)                        v = 0.5f * W3l[(size_t)o*K3 + k];          // Wa/2
            else if (k < 2*AF)                 v = W3l[(size_t)o*K3 + k];                 // Wj
            else if (k < K1)                   v = W3l[(size_t)o*K3 + 192 + (k-128)];     // Wij
        } else if (c >= 384){
            int o = c - 384;
            const float* W3l = W3 + (size_t)l*O1*K3;
            if (k < AF)                        v = 0.5f * W3l[(size_t)o*K3 + k];          // Wa/2
            else if (k < 2*AF)                 v = W3l[(size_t)o*K3 + k + AF];            // Wl
            else if (k < K1)                   v = W3l[(size_t)o*K3 + 233 + (k-128)];     // Wil
        }
        WALL[i] = __float2bfloat16(v);
    } else if (i < nW + NCONV*512){
        int m = i - nW;
        int l = m/512, c = m%512;
        float v = 0.f;
        if (c < O1)         v = fcb[l*O1 + c];
        else if (c < O1+OE) v = eb[l*OE + (c-O1)];
        else if (c >= 256)  v = 0.5f * b3[l*O1 + ((c-256)&127)];
        BIAS[m] = v;
    }
}

// ================= tot (bf16): [x | xn | e | 0], lda=192; 8 bf16 per thread
__global__ void gather_b(__hip_bfloat16* __restrict__ TOT, const float* __restrict__ X,
                         const float* __restrict__ E, const int* __restrict__ idx)
{
    int i = blockIdx.x*blockDim.x + threadIdx.x;
    if (i >= NM*24) return;
    int grp = i % 24, r = i / 24;
    int n = r / MNBR;
    float v[8];
    if (grp < 16){
        const float* src = (grp < 8) ? (X + (size_t)n*AF + grp*8)
                                     : (X + (size_t)idx[r]*AF + (grp-8)*8);
        #pragma unroll
        for (int j=0;j<8;j++) v[j] = src[j];
    } else {
        int base = (grp-16)*8;
        #pragma unroll
        for (int j=0;j<8;j++){
            int k = base + j;
            v[j] = (k < BFEA) ? E[(size_t)r*BFEA + k] : 0.f;
        }
    }
    __hip_bfloat16 o[8];
    #pragma unroll
    for (int j=0;j<8;j++) o[j] = __float2bfloat16(v[j]);
    *(uint4*)(TOT + (size_t)r*LDA_T + grp*8) = *(const uint4*)o;
}

// ================= fused stats: h/he column sums (210) + closed-form BN3 sums (no B!)
// block = 4 atoms (48 rows), 256 threads, grid 500
__global__ __launch_bounds__(256)
void stats_all(const float* __restrict__ REST,
               float* __restrict__ S1A, float* __restrict__ S2A,
               float* __restrict__ S13, float* __restrict__ S23)
{
    const int tid = threadIdx.x;
    const int n0 = blockIdx.x * 4;
    const int r0 = n0 * MNBR;
    if (tid < O1+OE){
        float s1 = 0.f, s2 = 0.f;
        #pragma unroll 4
        for (int j = 0; j < 4*MNBR; ++j){
            float v = REST[(size_t)(r0+j)*LDH + tid];
            s1 += v; s2 += v*v;
        }
        atomicAdd(&S1A[tid], s1);
        atomicAdd(&S2A[tid], s2);
    }
    if (tid < O1){
        float s1 = 0.f, s2 = 0.f;
        for (int a = 0; a < 4; ++a){
            int n = n0 + a;
            float sp=0.f, spp=0.f, sq=0.f, sqq=0.f;
            #pragma unroll
            for (int m=0;m<MNBR;m++){
                const float* row = REST + (size_t)(n*MNBR+m)*LDH;
                float p = row[256 + tid];
                float q = row[384 + tid];
                sp += p; spp += p*p; sq += q; sqq += q*q;
            }
            s1 += 12.f*(sp+sq);
            s2 += 12.f*(spp+sqq) + 2.f*sp*sq;
        }
        atomicAdd(&S13[tid], s1);
        atomicAdd(&S23[tid], s2);
    }
}

// ================= fused consumer (block = atom, 256 threads = 4 waves x 3 m's):
// inline BN finalize; two-body + three-body -> TB (+BN2 stats atomics); edge update
__global__ __launch_bounds__(256)
void consumer_k(const float* __restrict__ REST,
                const float* __restrict__ S1A, const float* __restrict__ S2A,
                const float* __restrict__ S13, const float* __restrict__ S23,
                const float* __restrict__ g1, const float* __restrict__ b1,
                const float* __restrict__ ge, const float* __restrict__ be,
                const float* __restrict__ g3, const float* __restrict__ b3b,
                float* __restrict__ TB, float* __restrict__ E,
                float* __restrict__ S12, float* __restrict__ S22)
{
    __shared__ float sA[O1+OE], tA[O1+OE], s3a[O1], t3a[O1];
    __shared__ float PS[MNBR][64], PB[MNBR][64], QS[MNBR][64], QB[MNBR][64];
    __shared__ float red[256];
    const int n = blockIdx.x;
    const int t = threadIdx.x;
    const int a = t & 63;
    const int g = t >> 6;
    const float invA = 1.f/(float)NM;
    const float inv3 = 1.f/((float)NM*MNBR);
    for (int c = t; c < O1+OE; c += 256){
        float mean = S1A[c]*invA;
        float var  = fmaxf(S2A[c]*invA - mean*mean, 0.f);
        float gg = (c < O1) ? g1[c] : ge[c-O1];
        float bb = (c < O1) ? b1[c] : be[c-O1];
        float sc = gg * rsqrtf(var + EPS_BN);
        sA[c] = sc; tA[c] = bb - sc*mean;
    }
    for (int c = t; c < O1; c += 256){
        float mean = S13[c]*inv3;
        float var  = fmaxf(S23[c]*inv3 - mean*mean, 0.f);
        float sc = g3[c] * rsqrtf(var + EPS_BN);
        s3a[c] = sc; t3a[c] = b3b[c] - sc*mean;
    }
    __syncthreads();

    // stage scaled P'/Q' (t3 folded into P side)
    float s3lo = s3a[a], s3hi = s3a[AF+a], t3lo = t3a[a], t3hi = t3a[AF+a];
    #pragma unroll
    for (int j=0;j<3;j++){
        int m = g*3 + j;
        const float* row = REST + (size_t)(n*MNBR+m)*LDH;
        PS[m][a] = s3lo*row[256+a] + t3lo;
        PB[m][a] = s3hi*row[320+a] + t3hi;
        QS[m][a] = s3lo*row[384+a];
        QB[m][a] = s3hi*row[448+a];
    }
    __syncthreads();

    float sha = sA[a], tha = tA[a], shb = sA[AF+a], thb = tA[AF+a];
    float acc = 0.f;
    float ua[3], ub[3];
    #pragma unroll
    for (int j=0;j<3;j++){
        int m = g*3 + j;
        const float* row = REST + (size_t)(n*MNBR+m)*LDH;
        acc += sigmoidf_(sha*row[a]+tha) * softplusf_(shb*row[AF+a]+thb);
        ua[j] = PS[m][a]; ub[j] = PB[m][a];
    }
    #pragma unroll
    for (int l2=0;l2<MNBR;l2++){
        float qa = QS[l2][a], qb = QB[l2][a];
        #pragma unroll
        for (int j=0;j<3;j++)
            acc += sigmoidf_(ua[j] + qa) * softplusf_(ub[j] + qb);
    }
    red[t] = acc;
    __syncthreads();
    if (g == 0){
        float tot = red[a] + red[64+a] + red[128+a] + red[192+a];
        TB[(size_t)n*AF + a] = tot;
        atomicAdd(&S12[a], tot);
        atomicAdd(&S22[a], tot*tot);
    }
    // edge update: 12*41 elements
    for (int idx = t; idx < MNBR*BFEA; idx += 256){
        int m = idx / BFEA, b = idx % BFEA;
        const float* row = REST + (size_t)(n*MNBR+m)*LDH;
        float u = sA[O1+b]*row[O1+b] + tA[O1+b];
        float v = sA[O1+BFEA+b]*row[O1+BFEA+b] + tA[O1+BFEA+b];
        E[(size_t)(n*MNBR+m)*BFEA + b] += sigmoidf_(u) * softplusf_(v);
    }
}

// ================= x = softplus(x + bn2(TB)), inline finalize
__global__ void x_update_k(float* __restrict__ X, const float* __restrict__ TB,
                           const float* __restrict__ S12, const float* __restrict__ S22,
                           const float* __restrict__ g2, const float* __restrict__ b2,
                           int total)
{
    int i = blockIdx.x*blockDim.x + threadIdx.x;
    if (i >= total) return;
    int a = i & (AF-1);
    float mean = S12[a]*(1.f/N_ATOM);
    float var  = fmaxf(S22[a]*(1.f/N_ATOM) - mean*mean, 0.f);
    float sc = g2[a]*rsqrtf(var + EPS_BN);
    X[i] = softplusf_(X[i] + sc*TB[i] + (b2[a] - sc*mean));
}

// ================= pooled mean per crystal + final dot
__global__ __launch_bounds__(128)
void pool_out_k(const float* __restrict__ Z, const int* __restrict__ seg,
                const float* __restrict__ outW, const float* __restrict__ outb,
                float* __restrict__ out)
{
    __shared__ float red[128];
    const int c = blockIdx.x;
    const int h = threadIdx.x;
    int l0, l1;
    {
        int l=0, r=N_ATOM;
        while (l<r){ int m=(l+r)>>1; if (seg[m] < c) l=m+1; else r=m; }
        l0 = l;
        l=l0; r=N_ATOM;
        while (l<r){ int m=(l+r)>>1; if (seg[m] < c+1) l=m+1; else r=m; }
        l1 = l;
    }
    float s = 0.f;
    for (int n = l0; n < l1; ++n) s += Z[(size_t)n*HID + h];
    float cnt = fmaxf((float)(l1-l0), 1.f);
    red[h] = (s/cnt) * outW[h];
    __syncthreads();
    for (int off=64; off>0; off>>=1){
        if (h < off) red[h] += red[h+off];
        __syncthreads();
    }
    if (h == 0) out[c] = red[0] + outb[0];
}

extern "C" void kernel_launch(void* const* d_in, const int* in_sizes, int n_in,
                              void* d_out, int out_size, void* d_ws, size_t ws_size,
                              hipStream_t stream)
{
    const float* atom_fea = (const float*)d_in[0];
    const float* nbr_fea  = (const float*)d_in[1];
    const int*   nbr_idx  = (const int*)d_in[2];
    const int*   site_seg = (const int*)d_in[3];
    const float* emb_W = (const float*)d_in[4];
    const float* emb_b = (const float*)d_in[5];
    const float* fcW   = (const float*)d_in[6];
    const float* fcb   = (const float*)d_in[7];
    const float* bn1_g = (const float*)d_in[8];
    const float* bn1_b = (const float*)d_in[9];
    const float* bn2_g = (const float*)d_in[10];
    const float* bn2_b = (const float*)d_in[11];
    const float* eW    = (const float*)d_in[12];
    const float* eb    = (const float*)d_in[13];
    const float* bne_g = (const float*)d_in[14];
    const float* bne_b = (const float*)d_in[15];
    const float* W3    = (const float*)d_in[16];
    const float* b3    = (const float*)d_in[17];
    const float* bn3_g = (const float*)d_in[18];
    const float* bn3_b = (const float*)d_in[19];
    const float* fc1W  = (const float*)d_in[20];
    const float* fc1b  = (const float*)d_in[21];
    const float* outW  = (const float*)d_in[22];
    const float* outb  = (const float*)d_in[23];

    // workspace layout (float units)
    float* ws   = (float*)d_ws;
    float* X    = ws;                        // 128000
    float* E    = ws + 128000;               // 984000
    __hip_bfloat16* TOT = (__hip_bfloat16*)(ws + 1112000);   // 24000*192 bf16
    float* REST = ws + 3416000;              // 24000*512 = 12288000
    float* TB   = ws + 15704000;             // 128000
    float* ST   = ws + 15832000;             // 3*2048
    __hip_bfloat16* WALL = (__hip_bfloat16*)(ws + 15838144); // 3*512*192 bf16
    float* BIAS = ws + 15985600;             // 1536 (+pad)
    float* Z    = ws + 15987200;             // 256000

    {
        int tot = NCONV*512*LDA_T + NCONV*512;
        pack_all<<<(tot+255)/256, 256, 0, stream>>>(fcW, eW, W3, fcb, eb, b3, WALL, BIAS);
    }
    hipMemsetAsync(ST, 0, NCONV*2048*sizeof(float), stream);
    gemm_tn<0,0><<<(N_ATOM+BM-1)/BM, 256, 0, stream>>>(atom_fea, OFEA, N_ATOM,
                                                       emb_W, OFEA, OFEA, AF, emb_b, X, AF);
    hipMemcpyAsync(E, nbr_fea, (size_t)NM*BFEA*sizeof(float),
                   hipMemcpyDeviceToDevice, stream);

    for (int i = 0; i < NCONV; i++){
        const float* g1 = bn1_g + i*O1, *b1 = bn1_b + i*O1;
        const float* g2 = bn2_g + i*AF, *b2 = bn2_b + i*AF;
        const float* ge = bne_g + i*OE, *be = bne_b + i*OE;
        const float* g3 = bn3_g + i*O1, *b3b = bn3_b + i*O1;
        float* STL = ST + i*2048;
        float *S1A=STL, *S2A=STL+256, *S13=STL+512, *S23=STL+640, *S12=STL+768, *S22=STL+832;

        gather_b<<<(NM*24+255)/256, 256, 0, stream>>>(TOT, X, E, nbr_idx);
        {
            dim3 g((NM+127)/128, 4);
            gemm_bf16<<<g, 256, 0, stream>>>(TOT, WALL + (size_t)i*512*LDA_T,
                                             BIAS + i*512, REST);
        }
        stats_all<<<N_ATOM/4, 256, 0, stream>>>(REST, S1A, S2A, S13, S23);
        consumer_k<<<N_ATOM, 256, 0, stream>>>(REST, S1A, S2A, S13, S23,
                                               g1, b1, ge, be, g3, b3b, TB, E, S12, S22);
        x_update_k<<<(N_ATOM*AF+255)/256, 256, 0, stream>>>(X, TB, S12, S22, g2, b2,
                                                            N_ATOM*AF);
    }

    // head: Z = softplus(softplus(X) @ fc1W^T + fc1b); pooled mean; out
    gemm_tn<1,1><<<(N_ATOM+BM-1)/BM, 256, 0, stream>>>(X, AF, N_ATOM, fc1W, AF, AF, HID,
                                                       fc1b, Z, HID);
    pool_out_k<<<NCRY, 128, 0, stream>>>(Z, site_seg, outW, outb, (float*)d_out);
}

// Round 6
// 508.573 us; speedup vs baseline: 2.6641x; 1.0121x over previous
//
#include <hip/hip_runtime.h>
#include <hip/hip_bf16.h>

// Problem constants
#define N_ATOM 2000
#define MNBR   12
#define OFEA   92
#define AF     64
#define BFEA   41
#define K1     169   // 2A+B
#define O1     128
#define OE     82
#define K3     274   // 3A+2B
#define NM     24000
#define NCONV  3
#define HID    128
#define NCRY   64
#define EPS_BN 1e-5f

#define LDA_T  192   // bf16 TOT leading dim (169 padded to 192)
#define LDH    512   // REST: [h(0..127)|he(128..209)|pad|P'(256..383)|Q'(384..511)]
#define LDSW   88    // LDS row pitch (ushorts) for MFMA tiles

typedef __bf16 bf16x8 __attribute__((ext_vector_type(8)));
typedef float  f32x4  __attribute__((ext_vector_type(4)));

__device__ __forceinline__ float sigmoidf_(float x){ return 1.f/(1.f+__expf(-x)); }
__device__ __forceinline__ float softplusf_(float x){
    return fmaxf(x,0.f) + __logf(1.f + __expf(-fabsf(x)));
}

// ================= bf16 MFMA GEMM: C[r,c] = bias[c] + sum_k A[r,k]*W[c,k]
__global__ __launch_bounds__(256)
void gemm_bf16(const __hip_bfloat16* __restrict__ A,
               const __hip_bfloat16* __restrict__ W,
               const float* __restrict__ bias,
               float* __restrict__ C)
{
    __shared__ unsigned short As[128][LDSW];
    __shared__ unsigned short Ws[128][LDSW];
    const int tid  = threadIdx.x;
    const int row0 = blockIdx.x * 128;
    const int col0 = blockIdx.y * 128;
    const int w    = tid >> 6;
    const int l    = tid & 63;
    const int wm   = w >> 1, wn = w & 1;
    const int lrow = l & 15;
    const int quad = l >> 4;

    f32x4 acc[4][4];
    #pragma unroll
    for (int i=0;i<4;i++)
        #pragma unroll
        for (int j=0;j<4;j++) acc[i][j] = (f32x4){0.f,0.f,0.f,0.f};

    for (int it = 0; it < 3; ++it){
        const int k0 = it * 64;
        if (it) __syncthreads();
        #pragma unroll
        for (int j = 0; j < 4; ++j){
            int e  = tid + j*256;
            int r  = e >> 3;
            int kk = (e & 7) << 3;
            int grow = row0 + r;
            uint4 va = make_uint4(0,0,0,0);
            if (grow < NM)
                va = *(const uint4*)(A + (size_t)grow*LDA_T + k0 + kk);
            *(uint4*)(&As[r][kk]) = va;
            uint4 vw = *(const uint4*)(W + (size_t)(col0 + r)*LDA_T + k0 + kk);
            *(uint4*)(&Ws[r][kk]) = vw;
        }
        __syncthreads();
        #pragma unroll
        for (int ks = 0; ks < 2; ++ks){
            int koff = ks*32 + quad*8;
            bf16x8 a_[4], b_[4];
            #pragma unroll
            for (int mi=0;mi<4;mi++)
                a_[mi] = *(const bf16x8*)(&As[wm*64 + mi*16 + lrow][koff]);
            #pragma unroll
            for (int ni=0;ni<4;ni++)
                b_[ni] = *(const bf16x8*)(&Ws[wn*64 + ni*16 + lrow][koff]);
            #pragma unroll
            for (int mi=0;mi<4;mi++)
                #pragma unroll
                for (int ni=0;ni<4;ni++)
                    acc[mi][ni] = __builtin_amdgcn_mfma_f32_16x16x32_bf16(
                        a_[mi], b_[ni], acc[mi][ni], 0, 0, 0);
        }
    }
    #pragma unroll
    for (int ni=0;ni<4;ni++){
        int col = col0 + wn*64 + ni*16 + lrow;
        float bv = bias[col];
        #pragma unroll
        for (int mi=0;mi<4;mi++){
            int rbase = row0 + wm*64 + mi*16 + quad*4;
            #pragma unroll
            for (int reg=0;reg<4;reg++){
                int grow = rbase + reg;
                if (grow < NM)
                    C[(size_t)grow*LDH + col] = acc[mi][ni][reg] + bv;
            }
        }
    }
}

// ================= small fp32 GEMM (embedding / head)
#define BM 64
#define BN 128
#define BK 32
template<int EPI, int SPIN>
__global__ __launch_bounds__(256)
void gemm_tn(const float* __restrict__ T, int ldt, int R,
             const float* __restrict__ W, int ldw, int K, int O,
             const float* __restrict__ bias,
             float* __restrict__ C, int ldc)
{
    __shared__ float Ts[BM][BK+1];
    __shared__ float Ws2[BN][BK+1];
    const int tid = threadIdx.x;
    const int row0 = blockIdx.x * BM;
    const int tx = tid % 16;
    const int ty = tid / 16;
    float acc[4][8];
    #pragma unroll
    for (int i=0;i<4;i++)
        #pragma unroll
        for (int j=0;j<8;j++) acc[i][j]=0.f;

    for (int k0 = 0; k0 < K; k0 += BK) {
        #pragma unroll
        for (int i=0;i<(BM*BK)/256;i++){
            int e = tid + i*256;
            int r = e / BK, k = e % BK;
            int gr = row0 + r, gk = k0 + k;
            float v = 0.f;
            if (gr < R && gk < K){
                v = T[(size_t)gr*ldt + gk];
                if (SPIN) v = softplusf_(v);
            }
            Ts[r][k] = v;
        }
        #pragma unroll
        for (int i=0;i<(BN*BK)/256;i++){
            int e = tid + i*256;
            int r = e / BK, k = e % BK;
            int gk = k0 + k;
            Ws2[r][k] = (r < O && gk < K) ? W[(size_t)r*ldw + gk] : 0.f;
        }
        __syncthreads();
        #pragma unroll
        for (int k=0;k<BK;k++){
            float a_[4], b_[8];
            #pragma unroll
            for (int i=0;i<4;i++) a_[i] = Ts[ty*4+i][k];
            #pragma unroll
            for (int j=0;j<8;j++) b_[j] = Ws2[tx + j*16][k];
            #pragma unroll
            for (int i=0;i<4;i++)
                #pragma unroll
                for (int j=0;j<8;j++)
                    acc[i][j] += a_[i]*b_[j];
        }
        __syncthreads();
    }
    #pragma unroll
    for (int i=0;i<4;i++){
        int gr = row0 + ty*4 + i;
        if (gr >= R) continue;
        #pragma unroll
        for (int j=0;j<8;j++){
            int gc = tx + j*16;
            if (gc >= O) continue;
            float v = acc[i][j] + (bias ? bias[gc] : 0.f);
            if (EPI==1) v = softplusf_(v);
            C[(size_t)gr*ldc + gc] = v;
        }
    }
}

// ================= pack weights (bf16) + bias (fp32).
__global__ void pack_all(const float* __restrict__ fcW, const float* __restrict__ eW,
                         const float* __restrict__ W3, const float* __restrict__ fcb,
                         const float* __restrict__ eb, const float* __restrict__ b3,
                         __hip_bfloat16* __restrict__ WALL, float* __restrict__ BIAS)
{
    int i = blockIdx.x*blockDim.x + threadIdx.x;
    const int nW = NCONV*512*LDA_T;
    if (i < nW){
        int l = i/(512*LDA_T), rem = i%(512*LDA_T);
        int c = rem/LDA_T, k = rem%LDA_T;
        float v = 0.f;
        if (c < O1){
            if (k < K1) v = fcW[((size_t)l*O1 + c)*K1 + k];
        } else if (c < O1+OE){
            if (k < K1) v = eW[((size_t)l*OE + (c-O1))*K1 + k];
        } else if (c >= 256 && c < 384){
            int o = c - 256;
            const float* W3l = W3 + (size_t)l*O1*K3;
            if (k < AF)                        v = 0.5f * W3l[(size_t)o*K3 + k];          // Wa/2
            else if (k < 2*AF)                 v = W3l[(size_t)o*K3 + k];                 // Wj
            else if (k < K1)                   v = W3l[(size_t)o*K3 + 192 + (k-128)];     // Wij
        } else if (c >= 384){
            int o = c - 384;
            const float* W3l = W3 + (size_t)l*O1*K3;
            if (k < AF)                        v = 0.5f * W3l[(size_t)o*K3 + k];          // Wa/2
            else if (k < 2*AF)                 v = W3l[(size_t)o*K3 + k + AF];            // Wl
            else if (k < K1)                   v = W3l[(size_t)o*K3 + 233 + (k-128)];     // Wil
        }
        WALL[i] = __float2bfloat16(v);
    } else if (i < nW + NCONV*512){
        int m = i - nW;
        int l = m/512, c = m%512;
        float v = 0.f;
        if (c < O1)         v = fcb[l*O1 + c];
        else if (c < O1+OE) v = eb[l*OE + (c-O1)];
        else if (c >= 256)  v = 0.5f * b3[l*O1 + ((c-256)&127)];
        BIAS[m] = v;
    }
}

// ================= tot (bf16): [x | xn | e | 0], lda=192; 8 bf16 per thread
__global__ void gather_b(__hip_bfloat16* __restrict__ TOT, const float* __restrict__ X,
                         const float* __restrict__ E, const int* __restrict__ idx)
{
    int i = blockIdx.x*blockDim.x + threadIdx.x;
    if (i >= NM*24) return;
    int grp = i % 24, r = i / 24;
    int n = r / MNBR;
    float v[8];
    if (grp < 16){
        const float* src = (grp < 8) ? (X + (size_t)n*AF + grp*8)
                                     : (X + (size_t)idx[r]*AF + (grp-8)*8);
        #pragma unroll
        for (int j=0;j<8;j++) v[j] = src[j];
    } else {
        int base = (grp-16)*8;
        #pragma unroll
        for (int j=0;j<8;j++){
            int k = base + j;
            v[j] = (k < BFEA) ? E[(size_t)r*BFEA + k] : 0.f;
        }
    }
    __hip_bfloat16 o[8];
    #pragma unroll
    for (int j=0;j<8;j++) o[j] = __float2bfloat16(v[j]);
    *(uint4*)(TOT + (size_t)r*LDA_T + grp*8) = *(const uint4*)o;
}

// ================= fused stats: h/he column sums (210) + closed-form BN3 sums
__global__ __launch_bounds__(256)
void stats_all(const float* __restrict__ REST,
               float* __restrict__ S1A, float* __restrict__ S2A,
               float* __restrict__ S13, float* __restrict__ S23)
{
    const int tid = threadIdx.x;
    const int n0 = blockIdx.x * 4;
    const int r0 = n0 * MNBR;
    if (tid < O1+OE){
        float s1 = 0.f, s2 = 0.f;
        #pragma unroll 4
        for (int j = 0; j < 4*MNBR; ++j){
            float v = REST[(size_t)(r0+j)*LDH + tid];
            s1 += v; s2 += v*v;
        }
        atomicAdd(&S1A[tid], s1);
        atomicAdd(&S2A[tid], s2);
    }
    if (tid < O1){
        float s1 = 0.f, s2 = 0.f;
        for (int a = 0; a < 4; ++a){
            int n = n0 + a;
            float sp=0.f, spp=0.f, sq=0.f, sqq=0.f;
            #pragma unroll
            for (int m=0;m<MNBR;m++){
                const float* row = REST + (size_t)(n*MNBR+m)*LDH;
                float p = row[256 + tid];
                float q = row[384 + tid];
                sp += p; spp += p*p; sq += q; sqq += q*q;
            }
            s1 += 12.f*(sp+sq);
            s2 += 12.f*(spp+sqq) + 2.f*sp*sq;
        }
        atomicAdd(&S13[tid], s1);
        atomicAdd(&S23[tid], s2);
    }
}

// ================= BN finalize for all channels -> packed SC table
// SC[0..209]=sA, SC[256..465]=tA, SC[512..639]=s3, SC[640..767]=t3
__global__ void bn_fin_all(const float* __restrict__ S1A, const float* __restrict__ S2A,
                           const float* __restrict__ S13, const float* __restrict__ S23,
                           const float* __restrict__ g1, const float* __restrict__ b1,
                           const float* __restrict__ ge, const float* __restrict__ be,
                           const float* __restrict__ g3, const float* __restrict__ b3b,
                           float* __restrict__ SC)
{
    int c = threadIdx.x;   // 256
    if (c < O1+OE){
        float mean = S1A[c]*(1.f/NM);
        float var  = fmaxf(S2A[c]*(1.f/NM) - mean*mean, 0.f);
        float gg = (c < O1) ? g1[c] : ge[c-O1];
        float bb = (c < O1) ? b1[c] : be[c-O1];
        float sc = gg * rsqrtf(var + EPS_BN);
        SC[c] = sc; SC[256+c] = bb - sc*mean;
    }
    if (c < O1){
        float mean = S13[c]*(1.f/((float)NM*MNBR));
        float var  = fmaxf(S23[c]*(1.f/((float)NM*MNBR)) - mean*mean, 0.f);
        float sc = g3[c] * rsqrtf(var + EPS_BN);
        SC[512+c] = sc; SC[640+c] = b3b[c] - sc*mean;
    }
}

// ================= consumer: block = atom, 256 threads (4 waves x 3 m's each).
// Q in registers; per-lane scalar scale loads (no prologue loop, 1 syncthreads).
__global__ __launch_bounds__(256)
void consumer_k(const float* __restrict__ REST, const float* __restrict__ SC,
                float* __restrict__ TB, float* __restrict__ E,
                float* __restrict__ S12, float* __restrict__ S22)
{
    __shared__ float red[256];
    const int n = blockIdx.x;
    const int t = threadIdx.x;
    const int a = t & 63;
    const int g = t >> 6;
    const float* base = REST + (size_t)n*MNBR*LDH;

    float sha = SC[a],      tha = SC[256+a];
    float shb = SC[64+a],   thb = SC[256+64+a];
    float s3lo = SC[512+a], s3hi = SC[512+64+a];
    float t3lo = SC[640+a], t3hi = SC[640+64+a];

    float Qa[MNBR], Qb[MNBR];
    #pragma unroll
    for (int m=0;m<MNBR;m++){
        const float* row = base + (size_t)m*LDH;
        Qa[m] = s3lo*row[384+a];
        Qb[m] = s3hi*row[448+a];
    }
    float acc = 0.f;
    #pragma unroll
    for (int j=0;j<3;j++){
        const float* row = base + (size_t)(g*3+j)*LDH;
        acc += sigmoidf_(sha*row[a]+tha) * softplusf_(shb*row[64+a]+thb);
        float ua = s3lo*row[256+a] + t3lo;
        float ub = s3hi*row[320+a] + t3hi;
        #pragma unroll
        for (int l2=0;l2<MNBR;l2++)
            acc += sigmoidf_(ua + Qa[l2]) * softplusf_(ub + Qb[l2]);
    }
    red[t] = acc;
    __syncthreads();
    if (g == 0){
        float tot = red[a] + red[64+a] + red[128+a] + red[192+a];
        TB[(size_t)n*AF + a] = tot;
        atomicAdd(&S12[a], tot);
        atomicAdd(&S22[a], tot*tot);
    }
    // edge update: idx = m*41+b consecutive -> coalesced E access
    for (int idx = t; idx < MNBR*BFEA; idx += 256){
        int m = idx / BFEA, b = idx % BFEA;
        const float* row = base + (size_t)m*LDH;
        float u = SC[O1+b]*row[O1+b]   + SC[256+O1+b];
        float v = SC[169+b]*row[169+b] + SC[256+169+b];
        E[(size_t)n*MNBR*BFEA + idx] += sigmoidf_(u) * softplusf_(v);
    }
}

// ================= x = softplus(x + bn2(TB)), inline finalize
__global__ void x_update_k(float* __restrict__ X, const float* __restrict__ TB,
                           const float* __restrict__ S12, const float* __restrict__ S22,
                           const float* __restrict__ g2, const float* __restrict__ b2,
                           int total)
{
    int i = blockIdx.x*blockDim.x + threadIdx.x;
    if (i >= total) return;
    int a = i & (AF-1);
    float mean = S12[a]*(1.f/N_ATOM);
    float var  = fmaxf(S22[a]*(1.f/N_ATOM) - mean*mean, 0.f);
    float sc = g2[a]*rsqrtf(var + EPS_BN);
    X[i] = softplusf_(X[i] + sc*TB[i] + (b2[a] - sc*mean));
}

// ================= pooled mean per crystal + final dot
__global__ __launch_bounds__(128)
void pool_out_k(const float* __restrict__ Z, const int* __restrict__ seg,
                const float* __restrict__ outW, const float* __restrict__ outb,
                float* __restrict__ out)
{
    __shared__ float red[128];
    const int c = blockIdx.x;
    const int h = threadIdx.x;
    int l0, l1;
    {
        int l=0, r=N_ATOM;
        while (l<r){ int m=(l+r)>>1; if (seg[m] < c) l=m+1; else r=m; }
        l0 = l;
        l=l0; r=N_ATOM;
        while (l<r){ int m=(l+r)>>1; if (seg[m] < c+1) l=m+1; else r=m; }
        l1 = l;
    }
    float s = 0.f;
    for (int n = l0; n < l1; ++n) s += Z[(size_t)n*HID + h];
    float cnt = fmaxf((float)(l1-l0), 1.f);
    red[h] = (s/cnt) * outW[h];
    __syncthreads();
    for (int off=64; off>0; off>>=1){
        if (h < off) red[h] += red[h+off];
        __syncthreads();
    }
    if (h == 0) out[c] = red[0] + outb[0];
}

extern "C" void kernel_launch(void* const* d_in, const int* in_sizes, int n_in,
                              void* d_out, int out_size, void* d_ws, size_t ws_size,
                              hipStream_t stream)
{
    const float* atom_fea = (const float*)d_in[0];
    const float* nbr_fea  = (const float*)d_in[1];
    const int*   nbr_idx  = (const int*)d_in[2];
    const int*   site_seg = (const int*)d_in[3];
    const float* emb_W = (const float*)d_in[4];
    const float* emb_b = (const float*)d_in[5];
    const float* fcW   = (const float*)d_in[6];
    const float* fcb   = (const float*)d_in[7];
    const float* bn1_g = (const float*)d_in[8];
    const float* bn1_b = (const float*)d_in[9];
    const float* bn2_g = (const float*)d_in[10];
    const float* bn2_b = (const float*)d_in[11];
    const float* eW    = (const float*)d_in[12];
    const float* eb    = (const float*)d_in[13];
    const float* bne_g = (const float*)d_in[14];
    const float* bne_b = (const float*)d_in[15];
    const float* W3    = (const float*)d_in[16];
    const float* b3    = (const float*)d_in[17];
    const float* bn3_g = (const float*)d_in[18];
    const float* bn3_b = (const float*)d_in[19];
    const float* fc1W  = (const float*)d_in[20];
    const float* fc1b  = (const float*)d_in[21];
    const float* outW  = (const float*)d_in[22];
    const float* outb  = (const float*)d_in[23];

    // workspace layout (float units)
    float* ws   = (float*)d_ws;
    float* X    = ws;                        // 128000
    float* E    = ws + 128000;               // 984000
    __hip_bfloat16* TOT = (__hip_bfloat16*)(ws + 1112000);   // 24000*192 bf16
    float* REST = ws + 3416000;              // 24000*512 = 12288000
    float* TB   = ws + 15704000;             // 128000
    float* ST   = ws + 15832000;             // 3*2048
    float* SC   = ws + 15838144;             // 1024
    __hip_bfloat16* WALL = (__hip_bfloat16*)(ws + 15839168); // 3*512*192 bf16
    float* BIAS = ws + 15986624;             // 1536 (+pad)
    float* Z    = ws + 15988224;             // 256000

    {
        int tot = NCONV*512*LDA_T + NCONV*512;
        pack_all<<<(tot+255)/256, 256, 0, stream>>>(fcW, eW, W3, fcb, eb, b3, WALL, BIAS);
    }
    hipMemsetAsync(ST, 0, NCONV*2048*sizeof(float), stream);
    gemm_tn<0,0><<<(N_ATOM+BM-1)/BM, 256, 0, stream>>>(atom_fea, OFEA, N_ATOM,
                                                       emb_W, OFEA, OFEA, AF, emb_b, X, AF);
    hipMemcpyAsync(E, nbr_fea, (size_t)NM*BFEA*sizeof(float),
                   hipMemcpyDeviceToDevice, stream);

    for (int i = 0; i < NCONV; i++){
        const float* g1 = bn1_g + i*O1, *b1 = bn1_b + i*O1;
        const float* g2 = bn2_g + i*AF, *b2 = bn2_b + i*AF;
        const float* ge = bne_g + i*OE, *be = bne_b + i*OE;
        const float* g3 = bn3_g + i*O1, *b3b = bn3_b + i*O1;
        float* STL = ST + i*2048;
        float *S1A=STL, *S2A=STL+256, *S13=STL+512, *S23=STL+640, *S12=STL+768, *S22=STL+832;

        gather_b<<<(NM*24+255)/256, 256, 0, stream>>>(TOT, X, E, nbr_idx);
        {
            dim3 g((NM+127)/128, 4);
            gemm_bf16<<<g, 256, 0, stream>>>(TOT, WALL + (size_t)i*512*LDA_T,
                                             BIAS + i*512, REST);
        }
        stats_all<<<N_ATOM/4, 256, 0, stream>>>(REST, S1A, S2A, S13, S23);
        bn_fin_all<<<1, 256, 0, stream>>>(S1A, S2A, S13, S23,
                                          g1, b1, ge, be, g3, b3b, SC);
        consumer_k<<<N_ATOM, 256, 0, stream>>>(REST, SC, TB, E, S12, S22);
        x_update_k<<<(N_ATOM*AF+255)/256, 256, 0, stream>>>(X, TB, S12, S22, g2, b2,
                                                            N_ATOM*AF);
    }

    // head: Z = softplus(softplus(X) @ fc1W^T + fc1b); pooled mean; out
    gemm_tn<1,1><<<(N_ATOM+BM-1)/BM, 256, 0, stream>>>(X, AF, N_ATOM, fc1W, AF, AF, HID,
                                                       fc1b, Z, HID);
    pool_out_k<<<NCRY, 128, 0, stream>>>(Z, site_seg, outW, outb, (float*)d_out);
}

// Round 7
// 423.342 us; speedup vs baseline: 3.2005x; 1.2013x over previous
//
#include <hip/hip_runtime.h>
#include <hip/hip_bf16.h>

// Problem constants
#define N_ATOM 2000
#define MNBR   12
#define OFEA   92
#define AF     64
#define BFEA   41
#define K1     169   // 2A+B
#define O1     128
#define OE     82
#define K3     274   // 3A+2B
#define NM     24000
#define NCONV  3
#define HID    128
#define NCRY   64
#define EPS_BN 1e-5f

#define LDA_T  192   // bf16 TOT leading dim (169 padded to 192)
#define LDH    512   // REST: [h(0..127)|he(128..209)|pad|P'(256..383)|Q'(384..511)]
#define LDSW   88    // LDS row pitch (ushorts) for MFMA tiles

typedef __bf16 bf16x8 __attribute__((ext_vector_type(8)));
typedef float  f32x4  __attribute__((ext_vector_type(4)));

// v_rcp_f32 (~1 ulp) instead of IEEE division sequence (~9 instrs)
__device__ __forceinline__ float sigmoidf_(float x){
    return __builtin_amdgcn_rcpf(1.f + __expf(-x));
}
__device__ __forceinline__ float softplusf_(float x){
    return fmaxf(x,0.f) + __logf(1.f + __expf(-fabsf(x)));
}

// ================= bf16 MFMA GEMM: C[r,c] = bias[c] + sum_k A[r,k]*W[c,k]
__global__ __launch_bounds__(256)
void gemm_bf16(const __hip_bfloat16* __restrict__ A,
               const __hip_bfloat16* __restrict__ W,
               const float* __restrict__ bias,
               float* __restrict__ C)
{
    __shared__ unsigned short As[128][LDSW];
    __shared__ unsigned short Ws[128][LDSW];
    const int tid  = threadIdx.x;
    const int row0 = blockIdx.x * 128;
    const int col0 = blockIdx.y * 128;
    const int w    = tid >> 6;
    const int l    = tid & 63;
    const int wm   = w >> 1, wn = w & 1;
    const int lrow = l & 15;
    const int quad = l >> 4;

    f32x4 acc[4][4];
    #pragma unroll
    for (int i=0;i<4;i++)
        #pragma unroll
        for (int j=0;j<4;j++) acc[i][j] = (f32x4){0.f,0.f,0.f,0.f};

    for (int it = 0; it < 3; ++it){
        const int k0 = it * 64;
        if (it) __syncthreads();
        #pragma unroll
        for (int j = 0; j < 4; ++j){
            int e  = tid + j*256;
            int r  = e >> 3;
            int kk = (e & 7) << 3;
            int grow = row0 + r;
            uint4 va = make_uint4(0,0,0,0);
            if (grow < NM)
                va = *(const uint4*)(A + (size_t)grow*LDA_T + k0 + kk);
            *(uint4*)(&As[r][kk]) = va;
            uint4 vw = *(const uint4*)(W + (size_t)(col0 + r)*LDA_T + k0 + kk);
            *(uint4*)(&Ws[r][kk]) = vw;
        }
        __syncthreads();
        #pragma unroll
        for (int ks = 0; ks < 2; ++ks){
            int koff = ks*32 + quad*8;
            bf16x8 a_[4], b_[4];
            #pragma unroll
            for (int mi=0;mi<4;mi++)
                a_[mi] = *(const bf16x8*)(&As[wm*64 + mi*16 + lrow][koff]);
            #pragma unroll
            for (int ni=0;ni<4;ni++)
                b_[ni] = *(const bf16x8*)(&Ws[wn*64 + ni*16 + lrow][koff]);
            #pragma unroll
            for (int mi=0;mi<4;mi++)
                #pragma unroll
                for (int ni=0;ni<4;ni++)
                    acc[mi][ni] = __builtin_amdgcn_mfma_f32_16x16x32_bf16(
                        a_[mi], b_[ni], acc[mi][ni], 0, 0, 0);
        }
    }
    #pragma unroll
    for (int ni=0;ni<4;ni++){
        int col = col0 + wn*64 + ni*16 + lrow;
        float bv = bias[col];
        #pragma unroll
        for (int mi=0;mi<4;mi++){
            int rbase = row0 + wm*64 + mi*16 + quad*4;
            #pragma unroll
            for (int reg=0;reg<4;reg++){
                int grow = rbase + reg;
                if (grow < NM)
                    C[(size_t)grow*LDH + col] = acc[mi][ni][reg] + bv;
            }
        }
    }
}

// ================= small fp32 GEMM (embedding / head)
#define BM 64
#define BN 128
#define BK 32
template<int EPI, int SPIN>
__global__ __launch_bounds__(256)
void gemm_tn(const float* __restrict__ T, int ldt, int R,
             const float* __restrict__ W, int ldw, int K, int O,
             const float* __restrict__ bias,
             float* __restrict__ C, int ldc)
{
    __shared__ float Ts[BM][BK+1];
    __shared__ float Ws2[BN][BK+1];
    const int tid = threadIdx.x;
    const int row0 = blockIdx.x * BM;
    const int tx = tid % 16;
    const int ty = tid / 16;
    float acc[4][8];
    #pragma unroll
    for (int i=0;i<4;i++)
        #pragma unroll
        for (int j=0;j<8;j++) acc[i][j]=0.f;

    for (int k0 = 0; k0 < K; k0 += BK) {
        #pragma unroll
        for (int i=0;i<(BM*BK)/256;i++){
            int e = tid + i*256;
            int r = e / BK, k = e % BK;
            int gr = row0 + r, gk = k0 + k;
            float v = 0.f;
            if (gr < R && gk < K){
                v = T[(size_t)gr*ldt + gk];
                if (SPIN) v = softplusf_(v);
            }
            Ts[r][k] = v;
        }
        #pragma unroll
        for (int i=0;i<(BN*BK)/256;i++){
            int e = tid + i*256;
            int r = e / BK, k = e % BK;
            int gk = k0 + k;
            Ws2[r][k] = (r < O && gk < K) ? W[(size_t)r*ldw + gk] : 0.f;
        }
        __syncthreads();
        #pragma unroll
        for (int k=0;k<BK;k++){
            float a_[4], b_[8];
            #pragma unroll
            for (int i=0;i<4;i++) a_[i] = Ts[ty*4+i][k];
            #pragma unroll
            for (int j=0;j<8;j++) b_[j] = Ws2[tx + j*16][k];
            #pragma unroll
            for (int i=0;i<4;i++)
                #pragma unroll
                for (int j=0;j<8;j++)
                    acc[i][j] += a_[i]*b_[j];
        }
        __syncthreads();
    }
    #pragma unroll
    for (int i=0;i<4;i++){
        int gr = row0 + ty*4 + i;
        if (gr >= R) continue;
        #pragma unroll
        for (int j=0;j<8;j++){
            int gc = tx + j*16;
            if (gc >= O) continue;
            float v = acc[i][j] + (bias ? bias[gc] : 0.f);
            if (EPI==1) v = softplusf_(v);
            C[(size_t)gr*ldc + gc] = v;
        }
    }
}

// ================= pack weights (bf16) + bias (fp32).
__global__ void pack_all(const float* __restrict__ fcW, const float* __restrict__ eW,
                         const float* __restrict__ W3, const float* __restrict__ fcb,
                         const float* __restrict__ eb, const float* __restrict__ b3,
                         __hip_bfloat16* __restrict__ WALL, float* __restrict__ BIAS)
{
    int i = blockIdx.x*blockDim.x + threadIdx.x;
    const int nW = NCONV*512*LDA_T;
    if (i < nW){
        int l = i/(512*LDA_T), rem = i%(512*LDA_T);
        int c = rem/LDA_T, k = rem%LDA_T;
        float v = 0.f;
        if (c < O1){
            if (k < K1) v = fcW[((size_t)l*O1 + c)*K1 + k];
        } else if (c < O1+OE){
            if (k < K1) v = eW[((size_t)l*OE + (c-O1))*K1 + k];
        } else if (c >= 256 && c < 384){
            int o = c - 256;
            const float* W3l = W3 + (size_t)l*O1*K3;
            if (k < AF)                        v = 0.5f * W3l[(size_t)o*K3 + k];          // Wa/2
            else if (k < 2*AF)                 v = W3l[(size_t)o*K3 + k];                 // Wj
            else if (k < K1)                   v = W3l[(size_t)o*K3 + 192 + (k-128)];     // Wij
        } else if (c >= 384){
            int o = c - 384;
            const float* W3l = W3 + (size_t)l*O1*K3;
            if (k < AF)                        v = 0.5f * W3l[(size_t)o*K3 + k];          // Wa/2
            else if (k < 2*AF)                 v = W3l[(size_t)o*K3 + k + AF];            // Wl
            else if (k < K1)                   v = W3l[(size_t)o*K3 + 233 + (k-128)];     // Wil
        }
        WALL[i] = __float2bfloat16(v);
    } else if (i < nW + NCONV*512){
        int m = i - nW;
        int l = m/512, c = m%512;
        float v = 0.f;
        if (c < O1)         v = fcb[l*O1 + c];
        else if (c < O1+OE) v = eb[l*OE + (c-O1)];
        else if (c >= 256)  v = 0.5f * b3[l*O1 + ((c-256)&127)];
        BIAS[m] = v;
    }
}

// ================= tot (bf16): [x | xn | e | 0], lda=192; 8 bf16 per thread
__global__ void gather_b(__hip_bfloat16* __restrict__ TOT, const float* __restrict__ X,
                         const float* __restrict__ E, const int* __restrict__ idx)
{
    int i = blockIdx.x*blockDim.x + threadIdx.x;
    if (i >= NM*24) return;
    int grp = i % 24, r = i / 24;
    int n = r / MNBR;
    float v[8];
    if (grp < 16){
        const float* src = (grp < 8) ? (X + (size_t)n*AF + grp*8)
                                     : (X + (size_t)idx[r]*AF + (grp-8)*8);
        #pragma unroll
        for (int j=0;j<8;j++) v[j] = src[j];
    } else {
        int base = (grp-16)*8;
        #pragma unroll
        for (int j=0;j<8;j++){
            int k = base + j;
            v[j] = (k < BFEA) ? E[(size_t)r*BFEA + k] : 0.f;
        }
    }
    __hip_bfloat16 o[8];
    #pragma unroll
    for (int j=0;j<8;j++) o[j] = __float2bfloat16(v[j]);
    *(uint4*)(TOT + (size_t)r*LDA_T + grp*8) = *(const uint4*)o;
}

// ================= fused stats: h/he column sums (210) + closed-form BN3 sums
__global__ __launch_bounds__(256)
void stats_all(const float* __restrict__ REST,
               float* __restrict__ S1A, float* __restrict__ S2A,
               float* __restrict__ S13, float* __restrict__ S23)
{
    const int tid = threadIdx.x;
    const int n0 = blockIdx.x * 4;
    const int r0 = n0 * MNBR;
    if (tid < O1+OE){
        float s1 = 0.f, s2 = 0.f;
        #pragma unroll 4
        for (int j = 0; j < 4*MNBR; ++j){
            float v = REST[(size_t)(r0+j)*LDH + tid];
            s1 += v; s2 += v*v;
        }
        atomicAdd(&S1A[tid], s1);
        atomicAdd(&S2A[tid], s2);
    }
    if (tid < O1){
        float s1 = 0.f, s2 = 0.f;
        for (int a = 0; a < 4; ++a){
            int n = n0 + a;
            float sp=0.f, spp=0.f, sq=0.f, sqq=0.f;
            #pragma unroll
            for (int m=0;m<MNBR;m++){
                const float* row = REST + (size_t)(n*MNBR+m)*LDH;
                float p = row[256 + tid];
                float q = row[384 + tid];
                sp += p; spp += p*p; sq += q; sqq += q*q;
            }
            s1 += 12.f*(sp+sq);
            s2 += 12.f*(spp+sqq) + 2.f*sp*sq;
        }
        atomicAdd(&S13[tid], s1);
        atomicAdd(&S23[tid], s2);
    }
}

// ================= BN finalize for all channels -> packed SC table
// SC[0..209]=sA, SC[256..465]=tA, SC[512..639]=s3, SC[640..767]=t3
__global__ void bn_fin_all(const float* __restrict__ S1A, const float* __restrict__ S2A,
                           const float* __restrict__ S13, const float* __restrict__ S23,
                           const float* __restrict__ g1, const float* __restrict__ b1,
                           const float* __restrict__ ge, const float* __restrict__ be,
                           const float* __restrict__ g3, const float* __restrict__ b3b,
                           float* __restrict__ SC)
{
    int c = threadIdx.x;   // 256
    if (c < O1+OE){
        float mean = S1A[c]*(1.f/NM);
        float var  = fmaxf(S2A[c]*(1.f/NM) - mean*mean, 0.f);
        float gg = (c < O1) ? g1[c] : ge[c-O1];
        float bb = (c < O1) ? b1[c] : be[c-O1];
        float sc = gg * rsqrtf(var + EPS_BN);
        SC[c] = sc; SC[256+c] = bb - sc*mean;
    }
    if (c < O1){
        float mean = S13[c]*(1.f/((float)NM*MNBR));
        float var  = fmaxf(S23[c]*(1.f/((float)NM*MNBR)) - mean*mean, 0.f);
        float sc = g3[c] * rsqrtf(var + EPS_BN);
        SC[512+c] = sc; SC[640+c] = b3b[c] - sc*mean;
    }
}

// ================= consumer: block = atom, 128 threads (2 waves x 6 m's each).
// Q in registers; no atomics; one syncthreads.
__global__ __launch_bounds__(128)
void consumer_k(const float* __restrict__ REST, const float* __restrict__ SC,
                float* __restrict__ TB, float* __restrict__ E)
{
    __shared__ float red[128];
    const int n = blockIdx.x;
    const int t = threadIdx.x;
    const int a = t & 63;
    const int g = t >> 6;     // 0..1
    const float* base = REST + (size_t)n*MNBR*LDH;

    float sha = SC[a],      tha = SC[256+a];
    float shb = SC[64+a],   thb = SC[256+64+a];
    float s3lo = SC[512+a], s3hi = SC[512+64+a];
    float t3lo = SC[640+a], t3hi = SC[640+64+a];

    float Qa[MNBR], Qb[MNBR];
    #pragma unroll
    for (int m=0;m<MNBR;m++){
        const float* row = base + (size_t)m*LDH;
        Qa[m] = s3lo*row[384+a];
        Qb[m] = s3hi*row[448+a];
    }
    float acc = 0.f;
    #pragma unroll
    for (int j=0;j<6;j++){
        const float* row = base + (size_t)(g*6+j)*LDH;
        acc += sigmoidf_(sha*row[a]+tha) * softplusf_(shb*row[64+a]+thb);
        float ua = s3lo*row[256+a] + t3lo;
        float ub = s3hi*row[320+a] + t3hi;
        #pragma unroll
        for (int l2=0;l2<MNBR;l2++)
            acc += sigmoidf_(ua + Qa[l2]) * softplusf_(ub + Qb[l2]);
    }
    red[t] = acc;
    __syncthreads();
    if (g == 0)
        TB[(size_t)n*AF + a] = red[a] + red[64+a];
    // edge update: idx = m*41+b consecutive -> coalesced E access
    for (int idx = t; idx < MNBR*BFEA; idx += 128){
        int m = idx / BFEA, b = idx % BFEA;
        const float* row = base + (size_t)m*LDH;
        float u = SC[O1+b]*row[O1+b]   + SC[256+O1+b];
        float v = SC[169+b]*row[169+b] + SC[256+169+b];
        E[(size_t)n*MNBR*BFEA + idx] += sigmoidf_(u) * softplusf_(v);
    }
}

// ================= per-column sum/sumsq for TB (R4-style, no consumer atomics)
__global__ __launch_bounds__(64)
void tb_stats_k(const float* __restrict__ TB,
                float* __restrict__ S1, float* __restrict__ S2)
{
    int t = threadIdx.x;
    float s1 = 0.f, s2 = 0.f;
    for (int r = blockIdx.x; r < N_ATOM; r += gridDim.x){
        float v = TB[(size_t)r*AF + t];
        s1 += v; s2 += v*v;
    }
    atomicAdd(&S1[t], s1);
    atomicAdd(&S2[t], s2);
}

// ================= x = softplus(x + bn2(TB)), inline finalize
__global__ void x_update_k(float* __restrict__ X, const float* __restrict__ TB,
                           const float* __restrict__ S12, const float* __restrict__ S22,
                           const float* __restrict__ g2, const float* __restrict__ b2,
                           int total)
{
    int i = blockIdx.x*blockDim.x + threadIdx.x;
    if (i >= total) return;
    int a = i & (AF-1);
    float mean = S12[a]*(1.f/N_ATOM);
    float var  = fmaxf(S22[a]*(1.f/N_ATOM) - mean*mean, 0.f);
    float sc = g2[a]*rsqrtf(var + EPS_BN);
    X[i] = softplusf_(X[i] + sc*TB[i] + (b2[a] - sc*mean));
}

// ================= pooled mean per crystal + final dot
__global__ __launch_bounds__(128)
void pool_out_k(const float* __restrict__ Z, const int* __restrict__ seg,
                const float* __restrict__ outW, const float* __restrict__ outb,
                float* __restrict__ out)
{
    __shared__ float red[128];
    const int c = blockIdx.x;
    const int h = threadIdx.x;
    int l0, l1;
    {
        int l=0, r=N_ATOM;
        while (l<r){ int m=(l+r)>>1; if (seg[m] < c) l=m+1; else r=m; }
        l0 = l;
        l=l0; r=N_ATOM;
        while (l<r){ int m=(l+r)>>1; if (seg[m] < c+1) l=m+1; else r=m; }
        l1 = l;
    }
    float s = 0.f;
    for (int n = l0; n < l1; ++n) s += Z[(size_t)n*HID + h];
    float cnt = fmaxf((float)(l1-l0), 1.f);
    red[h] = (s/cnt) * outW[h];
    __syncthreads();
    for (int off=64; off>0; off>>=1){
        if (h < off) red[h] += red[h+off];
        __syncthreads();
    }
    if (h == 0) out[c] = red[0] + outb[0];
}

extern "C" void kernel_launch(void* const* d_in, const int* in_sizes, int n_in,
                              void* d_out, int out_size, void* d_ws, size_t ws_size,
                              hipStream_t stream)
{
    const float* atom_fea = (const float*)d_in[0];
    const float* nbr_fea  = (const float*)d_in[1];
    const int*   nbr_idx  = (const int*)d_in[2];
    const int*   site_seg = (const int*)d_in[3];
    const float* emb_W = (const float*)d_in[4];
    const float* emb_b = (const float*)d_in[5];
    const float* fcW   = (const float*)d_in[6];
    const float* fcb   = (const float*)d_in[7];
    const float* bn1_g = (const float*)d_in[8];
    const float* bn1_b = (const float*)d_in[9];
    const float* bn2_g = (const float*)d_in[10];
    const float* bn2_b = (const float*)d_in[11];
    const float* eW    = (const float*)d_in[12];
    const float* eb    = (const float*)d_in[13];
    const float* bne_g = (const float*)d_in[14];
    const float* bne_b = (const float*)d_in[15];
    const float* W3    = (const float*)d_in[16];
    const float* b3    = (const float*)d_in[17];
    const float* bn3_g = (const float*)d_in[18];
    const float* bn3_b = (const float*)d_in[19];
    const float* fc1W  = (const float*)d_in[20];
    const float* fc1b  = (const float*)d_in[21];
    const float* outW  = (const float*)d_in[22];
    const float* outb  = (const float*)d_in[23];

    // workspace layout (float units)
    float* ws   = (float*)d_ws;
    float* X    = ws;                        // 128000
    float* E    = ws + 128000;               // 984000
    __hip_bfloat16* TOT = (__hip_bfloat16*)(ws + 1112000);   // 24000*192 bf16
    float* REST = ws + 3416000;              // 24000*512 = 12288000
    float* TB   = ws + 15704000;             // 128000
    float* ST   = ws + 15832000;             // 3*2048
    float* SC   = ws + 15838144;             // 1024
    __hip_bfloat16* WALL = (__hip_bfloat16*)(ws + 15839168); // 3*512*192 bf16
    float* BIAS = ws + 15986624;             // 1536 (+pad)
    float* Z    = ws + 15988224;             // 256000

    {
        int tot = NCONV*512*LDA_T + NCONV*512;
        pack_all<<<(tot+255)/256, 256, 0, stream>>>(fcW, eW, W3, fcb, eb, b3, WALL, BIAS);
    }
    hipMemsetAsync(ST, 0, NCONV*2048*sizeof(float), stream);
    gemm_tn<0,0><<<(N_ATOM+BM-1)/BM, 256, 0, stream>>>(atom_fea, OFEA, N_ATOM,
                                                       emb_W, OFEA, OFEA, AF, emb_b, X, AF);
    hipMemcpyAsync(E, nbr_fea, (size_t)NM*BFEA*sizeof(float),
                   hipMemcpyDeviceToDevice, stream);

    for (int i = 0; i < NCONV; i++){
        const float* g1 = bn1_g + i*O1, *b1 = bn1_b + i*O1;
        const float* g2 = bn2_g + i*AF, *b2 = bn2_b + i*AF;
        const float* ge = bne_g + i*OE, *be = bne_b + i*OE;
        const float* g3 = bn3_g + i*O1, *b3b = bn3_b + i*O1;
        float* STL = ST + i*2048;
        float *S1A=STL, *S2A=STL+256, *S13=STL+512, *S23=STL+640, *S12=STL+768, *S22=STL+832;

        gather_b<<<(NM*24+255)/256, 256, 0, stream>>>(TOT, X, E, nbr_idx);
        {
            dim3 g((NM+127)/128, 4);
            gemm_bf16<<<g, 256, 0, stream>>>(TOT, WALL + (size_t)i*512*LDA_T,
                                             BIAS + i*512, REST);
        }
        stats_all<<<N_ATOM/4, 256, 0, stream>>>(REST, S1A, S2A, S13, S23);
        bn_fin_all<<<1, 256, 0, stream>>>(S1A, S2A, S13, S23,
                                          g1, b1, ge, be, g3, b3b, SC);
        consumer_k<<<N_ATOM, 128, 0, stream>>>(REST, SC, TB, E);
        tb_stats_k<<<128, 64, 0, stream>>>(TB, S12, S22);
        x_update_k<<<(N_ATOM*AF+255)/256, 256, 0, stream>>>(X, TB, S12, S22, g2, b2,
                                                            N_ATOM*AF);
    }

    // head: Z = softplus(softplus(X) @ fc1W^T + fc1b); pooled mean; out
    gemm_tn<1,1><<<(N_ATOM+BM-1)/BM, 256, 0, stream>>>(X, AF, N_ATOM, fc1W, AF, AF, HID,
                                                       fc1b, Z, HID);
    pool_out_k<<<NCRY, 128, 0, stream>>>(Z, site_seg, outW, outb, (float*)d_out);
}